// Round 9
// baseline (4549.458 us; speedup 1.0000x reference)
//
#include <hip/hip_runtime.h>
#include <math.h>

// Problem dims
constexpr int Bsz  = 512;
constexpr int Nseq = 64;
constexpr int DX   = 4;
constexpr int MET  = 4;
constexpr int Hd   = 512;
constexpr int H3d  = 1536;

constexpr float RTOL_C = 1e-3f;
constexpr float ATOL_C = 1e-5f;

// ---- Dopri5 tableau (exactly as in jax.experimental.ode, f64->f32) ----
constexpr float SB10 = (float)(1.0/5.0);
constexpr float SB20 = (float)(3.0/40.0),  SB21 = (float)(9.0/40.0);
constexpr float SB30 = (float)(44.0/45.0), SB31 = (float)(-56.0/15.0), SB32 = (float)(32.0/9.0);
constexpr float SB40 = (float)(19372.0/6561.0), SB41 = (float)(-25360.0/2187.0),
                SB42 = (float)(64448.0/6561.0), SB43 = (float)(-212.0/729.0);
constexpr float SB50 = (float)(9017.0/3168.0),  SB51 = (float)(-355.0/33.0),
                SB52 = (float)(46732.0/5247.0), SB53 = (float)(49.0/176.0),
                SB54 = (float)(-5103.0/18656.0);
constexpr float CS0 = (float)(35.0/384.0), CS2 = (float)(500.0/1113.0),
                CS3 = (float)(125.0/192.0), CS4 = (float)(-2187.0/6784.0),
                CS5 = (float)(11.0/84.0);
// Shampine error coefficients (c_sol - c_star), as written in jax ode.py
constexpr float CE0 = (float)(35.0/384.0 - 1951.0/21600.0);
constexpr float CE2 = (float)(500.0/1113.0 - 22642.0/50085.0);
constexpr float CE3 = (float)(125.0/192.0 - 451.0/720.0);
constexpr float CE4 = (float)(-2187.0/6784.0 + 12231.0/42400.0);
constexpr float CE5 = (float)(11.0/84.0 - 649.0/6300.0);
constexpr float CE6 = (float)(-1.0/60.0);
// dps_c_mid for interpolation fit
constexpr float CM0 = (float)(6025192743.0/30085553152.0/2.0);
constexpr float CM2 = (float)(51252292925.0/65400821598.0/2.0);
constexpr float CM3 = (float)(-2691868925.0/45128329728.0/2.0);
constexpr float CM4 = (float)(187940372067.0/1594534317056.0/2.0);
constexpr float CM5 = (float)(-1776094331.0/19743644256.0/2.0);
constexpr float CM6 = (float)(11237099.0/235043384.0/2.0);

__device__ __forceinline__ float selu_f(float v) {
  const float scl = 1.0507009873554805f;
  const float alp = 1.6732632423543772f;
  float e = v > 0.f ? v : alp * expm1f(v);
  return scl * e;
}
__device__ __forceinline__ float sigmoid_f(float v) {
  return 1.f / (1.f + expf(-v));
}

// ---------------- fused weight repack (one launch) ----------------
__global__ __launch_bounds__(256) void pack_all_kernel(
    const float* __restrict__ gWhh, const float* __restrict__ gWih,
    const float* __restrict__ eW1,  const float* __restrict__ eW2,
    const float* __restrict__ oW1,  const float* __restrict__ oW2,
    float* __restrict__ WhhP, float* __restrict__ WihT,
    float* __restrict__ eW1P, float* __restrict__ eW2P,
    float* __restrict__ oW1P, float* __restrict__ oW2P)
{
  int i = blockIdx.x * 256 + threadIdx.x;
  if (i < 786432) {
    const int r = i >> 9, k = i & 511;
    WhhP[(k >> 2) * (H3d * 4) + r * 4 + (k & 3)] = gWhh[i];
  } else if (i < 798720) {
    const int ii = i - 786432;
    const int r = ii >> 3, c = ii & 7;
    WihT[c * H3d + r] = gWih[ii];
  } else if (i < 1060864) {
    const int ii = i - 798720;
    const int r = ii >> 9, k = ii & 511;
    eW1P[(k >> 2) * (Hd * 4) + r * 4 + (k & 3)] = eW1[ii];
  } else if (i < 1585152) {
    const int ii = i - 1060864;
    const int r = ii >> 9, k = ii & 511;
    eW2P[(k >> 2) * (1024 * 4) + r * 4 + (k & 3)] = eW2[ii];
  } else if (i < 1847296) {
    const int ii = i - 1585152;
    const int r = ii >> 9, k = ii & 511;
    oW1P[(k >> 2) * (Hd * 4) + r * 4 + (k & 3)] = oW1[ii];
  } else if (i < 2109440) {
    const int ii = i - 1847296;
    const int r = ii >> 9, k = ii & 511;
    oW2P[(k >> 2) * (Hd * 4) + r * 4 + (k & 3)] = oW2[ii];
  }
}

// ---------------- GRU step: h_out = GRUCell(xm_t, h_in) ----------------
// grid (32,8) = 256 blocks (1/CU), 256 threads = 4 waves; wave rg owns rows
// 4rg..4rg+3 -> 4 rows/thread. Per-CU register-delivery per step:
// 4 waves x 384KB slice = 1.5MB (R6 was 3MB@26us, R8 was 6MB@45us -- time
// scales with delivered bytes at ~64B/cyc L1 return). Each weight float4 now
// feeds 12 FMAs. FMA floor 5.9us; delivery ~11.5us; predict ~13-16us/step.
// Per-(b,j) FMA chain identical to all prior rounds -> bit-identical h.
__global__ __launch_bounds__(256) void gru_step_kernel(
    const float* __restrict__ x, const float* __restrict__ meta,
    const float* __restrict__ WihT, const float* __restrict__ WhhP,
    const float* __restrict__ bih, const float* __restrict__ bhh,
    const float* __restrict__ h_in, float* __restrict__ h_out, int t)
{
  __shared__ __align__(16) float hs[16][Hd];     // 32 KB h tile
  const int tid = threadIdx.x;
  const int jl  = tid & 63;
  const int rg  = tid >> 6;                      // wave 0..3 -> rows 4rg..4rg+3
  const int j   = blockIdx.y * 64 + jl;
  const int b0  = blockIdx.x * 16;

  // stage 16x512 h tile (coalesced float4, 8 per thread)
  for (int i = tid; i < 16 * Hd / 4; i += 256)
    *(float4*)&hs[0][i * 4] = *(const float4*)&h_in[b0 * Hd + i * 4];
  __syncthreads();

  float ar[4] = {0.f, 0.f, 0.f, 0.f};
  float az[4] = {0.f, 0.f, 0.f, 0.f};
  float an[4] = {0.f, 0.f, 0.f, 0.f};
#pragma unroll 4
  for (int k4 = 0; k4 < Hd / 4; ++k4) {
    const float4 wr = *(const float4*)&WhhP[(k4 * H3d + j) * 4];
    const float4 wz = *(const float4*)&WhhP[(k4 * H3d + 512 + j) * 4];
    const float4 wn = *(const float4*)&WhhP[(k4 * H3d + 1024 + j) * 4];
#pragma unroll
    for (int m = 0; m < 4; ++m) {
      const float4 hv = *(const float4*)&hs[rg * 4 + m][k4 * 4];  // broadcast
      ar[m] += wr.x * hv.x + wr.y * hv.y + wr.z * hv.z + wr.w * hv.w;
      az[m] += wz.x * hv.x + wz.y * hv.y + wz.z * hv.z + wz.w * hv.w;
      an[m] += wn.x * hv.x + wn.y * hv.y + wn.z * hv.z + wn.w * hv.w;
    }
  }

  const float bihr = bih[j], bihz = bih[512 + j], bihn = bih[1024 + j];
  const float bhhr = bhh[j], bhhz = bhh[512 + j], bhhn = bhh[1024 + j];
  float wir[8], wiz[8], win[8];
#pragma unroll
  for (int kk = 0; kk < 8; ++kk) {
    wir[kk] = WihT[kk * H3d + j];
    wiz[kk] = WihT[kk * H3d + 512 + j];
    win[kk] = WihT[kk * H3d + 1024 + j];
  }

#pragma unroll
  for (int m = 0; m < 4; ++m) {
    const int bl = rg * 4 + m;
    const int b  = b0 + bl;
    const float4 xv = *(const float4*)&x[(b * Nseq + t) * DX];
    const float4 mv = *(const float4*)&meta[b * MET];
    float xm[8] = { xv.x, xv.y, xv.z, xv.w, mv.x, mv.y, mv.z, mv.w };
    float gr = bihr, gz = bihz, gn = bihn;
#pragma unroll
    for (int kk = 0; kk < 8; ++kk) {
      gr += xm[kk] * wir[kk];
      gz += xm[kk] * wiz[kk];
      gn += xm[kk] * win[kk];
    }
    const float r = sigmoid_f(gr + ar[m] + bhhr);
    const float z = sigmoid_f(gz + az[m] + bhhz);
    const float n = tanhf(gn + r * (an[m] + bhhn));
    const float hold = hs[bl][j];
    h_out[b * Hd + j] = (1.f - z) * n + z * hold;
  }
}

// ---------------- encoder layer 1: relu(A @ W^T + b) ----------------
__global__ __launch_bounds__(256) void gemm_relu_kernel(
    const float* __restrict__ A, const float* __restrict__ WP,
    const float* __restrict__ bias, float* __restrict__ Cout)
{
  __shared__ __align__(16) float as[16 * Hd];
  const int tid  = threadIdx.x;
  const int jl   = tid & 63;
  const int bsub = tid >> 6;
  const int j    = blockIdx.y * 64 + jl;
  const int b0   = blockIdx.x * 16;

  for (int i = tid; i < 16 * Hd; i += 256) as[i] = A[b0 * Hd + i];
  __syncthreads();

  float acc[4] = {0.f, 0.f, 0.f, 0.f};
#pragma unroll 2
  for (int k4 = 0; k4 < Hd / 4; ++k4) {
    const float4 w = *(const float4*)&WP[(k4 * Hd + j) * 4];
#pragma unroll
    for (int m = 0; m < 4; ++m) {
      const float4 av = *(const float4*)&as[(bsub * 4 + m) * Hd + k4 * 4];
      acc[m] += w.x * av.x + w.y * av.y + w.z * av.z + w.w * av.w;
    }
  }
  const float bj = bias[j];
#pragma unroll
  for (int m = 0; m < 4; ++m) {
    const int b = b0 + bsub * 4 + m;
    float v = acc[m] + bj;
    Cout[b * Hd + j] = v > 0.f ? v : 0.f;
  }
}

// ---------------- encoder layer 2 + reparam: z0 = eps*std + mean ----------------
__global__ __launch_bounds__(256) void enc2_z0_kernel(
    const float* __restrict__ O1, const float* __restrict__ W2P,  // [k4][1024][4]
    const float* __restrict__ b2, const float* __restrict__ eps,
    float* __restrict__ z0)
{
  __shared__ __align__(16) float as[16 * Hd];
  const int tid  = threadIdx.x;
  const int jl   = tid & 63;
  const int bsub = tid >> 6;
  const int j    = blockIdx.y * 64 + jl;
  const int b0   = blockIdx.x * 16;

  for (int i = tid; i < 16 * Hd; i += 256) as[i] = O1[b0 * Hd + i];
  __syncthreads();

  float am[4] = {0.f, 0.f, 0.f, 0.f};
  float asd[4] = {0.f, 0.f, 0.f, 0.f};
#pragma unroll 2
  for (int k4 = 0; k4 < Hd / 4; ++k4) {
    const float4 wm = *(const float4*)&W2P[(k4 * 1024 + j) * 4];
    const float4 ws = *(const float4*)&W2P[(k4 * 1024 + 512 + j) * 4];
#pragma unroll
    for (int m = 0; m < 4; ++m) {
      const float4 av = *(const float4*)&as[(bsub * 4 + m) * Hd + k4 * 4];
      am[m]  += wm.x * av.x + wm.y * av.y + wm.z * av.z + wm.w * av.w;
      asd[m] += ws.x * av.x + ws.y * av.y + ws.z * av.z + ws.w * av.w;
    }
  }
  const float bm = b2[j], bs = b2[512 + j];
#pragma unroll
  for (int m = 0; m < 4; ++m) {
    const int b = b0 + bsub * 4 + m;
    const float mean = am[m] + bm;
    const float sd   = asd[m] + bs;
    z0[b * Hd + j] = eps[b * Hd + j] * sd + mean;
  }
}

// ---------------- adaptive Dopri5 ODE solve + final FC ----------------
// 256 blocks x 512 threads, GE=2. Structural floor: each drift streams
// W1+W2 = 2MB through each CU's register path exactly once (no wave
// redundancy: each wave covers distinct j). ~11-12 lockstep iters x 6
// drifts x ~15us = the measured ~1070us.
__global__ __launch_bounds__(512) void ode_fc_kernel(
    const float* __restrict__ x, const float* __restrict__ meta,
    const float* __restrict__ z0in,
    const float* __restrict__ W1P, const float* __restrict__ b1v,
    const float* __restrict__ W2P, const float* __restrict__ b2v,
    const float* __restrict__ fcW, const float* __restrict__ fcb,
    float* __restrict__ outp)
{
  constexpr int GE = 2;
  __shared__ __align__(16) float zsh[GE][Hd];   // 4 KB
  __shared__ float red[8 * GE];
  const int tid = threadIdx.x;
  const int jj  = tid & 255;
  const int eh  = tid >> 8;            // element 0/1 (wave-uniform)
  const int j1  = jj + 256;
  const int bg0 = blockIdx.x * GE;

  const float b1a = b1v[jj], b1b = b1v[j1];
  const float b2a = b2v[jj], b2b = b2v[j1];

  // drift for the thread's 2 (j, eh) slots
  auto drift = [&](const float (&in)[2], float (&out)[2]) {
    __syncthreads();
    zsh[eh][jj] = in[0];
    zsh[eh][j1] = in[1];
    __syncthreads();
    float u0 = b1a, u1 = b1b;
#pragma unroll 4
    for (int k4 = 0; k4 < Hd / 4; ++k4) {
      const float4 wA = *(const float4*)&W1P[(k4 * Hd + jj) * 4];
      const float4 wB = *(const float4*)&W1P[(k4 * Hd + j1) * 4];
      const float4 z  = *(const float4*)&zsh[eh][k4 * 4];
      u0 += wA.x * z.x + wA.y * z.y + wA.z * z.z + wA.w * z.w;
      u1 += wB.x * z.x + wB.y * z.y + wB.z * z.z + wB.w * z.w;
    }
    u0 = selu_f(u0); u1 = selu_f(u1);
    __syncthreads();
    zsh[eh][jj] = u0;
    zsh[eh][j1] = u1;
    __syncthreads();
    float v0 = b2a, v1 = b2b;
#pragma unroll 4
    for (int k4 = 0; k4 < Hd / 4; ++k4) {
      const float4 wA = *(const float4*)&W2P[(k4 * Hd + jj) * 4];
      const float4 wB = *(const float4*)&W2P[(k4 * Hd + j1) * 4];
      const float4 z  = *(const float4*)&zsh[eh][k4 * 4];
      v0 += wA.x * z.x + wA.y * z.y + wA.z * z.z + wA.w * z.w;
      v1 += wB.x * z.x + wB.y * z.y + wB.z * z.z + wB.w * z.w;
    }
    out[0] = v0; out[1] = v1;
  };

  // block-wide per-element sum; all threads receive identical results
  auto blocksum = [&](float (&v)[GE], float (&s)[GE]) {
#pragma unroll
    for (int off = 32; off > 0; off >>= 1) {
#pragma unroll
      for (int g = 0; g < GE; ++g) v[g] += __shfl_down(v[g], off);
    }
    __syncthreads();
    if ((tid & 63) == 0) {
      const int w = tid >> 6;
#pragma unroll
      for (int g = 0; g < GE; ++g) red[w * GE + g] = v[g];
    }
    __syncthreads();
#pragma unroll
    for (int g = 0; g < GE; ++g) {
      float t = 0.f;
#pragma unroll
      for (int w = 0; w < 8; ++w) t += red[w * GE + g];
      s[g] = t;
    }
  };

  float y[2], f[2], py[2], pf[2], ym[2];
  float tcur[GE], dtv[GE], tfin[GE], ptv[GE], pdt[GE];
  bool act[GE];

  y[0] = z0in[(bg0 + eh) * Hd + jj];
  y[1] = z0in[(bg0 + eh) * Hd + j1];
#pragma unroll
  for (int g = 0; g < GE; ++g) {
    tcur[g] = x[((bg0 + g) * Nseq + 0) * DX];
    tfin[g] = x[((bg0 + g) * Nseq + (Nseq - 1)) * DX];
  }

  drift(y, f);

  // ---- initial step size (Hairer / jax variant) ----
  float sc[2];
  float q0[GE] = {0.f, 0.f}, q1[GE] = {0.f, 0.f};
#pragma unroll
  for (int l = 0; l < 2; ++l) {
    sc[l] = ATOL_C + RTOL_C * fabsf(y[l]);
    const float a = y[l] / sc[l], b = f[l] / sc[l];
    q0[eh] += a * a;
    q1[eh] += b * b;
  }
  float d0s[GE], d1s[GE];
  blocksum(q0, d0s);
  blocksum(q1, d1s);
  float h0[GE];
#pragma unroll
  for (int g = 0; g < GE; ++g) {
    const float d0 = sqrtf(d0s[g]), d1 = sqrtf(d1s[g]);
    h0[g] = (d0 < 1e-5f || d1 < 1e-5f) ? 1e-6f : 0.01f * d0 / d1;
  }
  float yin[2], f1h[2];
#pragma unroll
  for (int l = 0; l < 2; ++l) yin[l] = y[l] + h0[eh] * f[l];
  drift(yin, f1h);
  float q2[GE] = {0.f, 0.f};
#pragma unroll
  for (int l = 0; l < 2; ++l) {
    const float dd = (f1h[l] - f[l]) / sc[l];
    q2[eh] += dd * dd;
  }
  float d2s[GE];
  blocksum(q2, d2s);
#pragma unroll
  for (int g = 0; g < GE; ++g) {
    const float d1 = sqrtf(d1s[g]);
    const float d2 = sqrtf(d2s[g]) / h0[g];
    const float h1 = (d1 <= 1e-15f && d2 <= 1e-15f)
                 ? fmaxf(1e-6f, h0[g] * 1e-3f)
                 : powf(0.01f / (d1 + d2), 0.2f);   // jax uses d1+d2 here
    dtv[g] = fminf(100.f * h0[g], h1);
    ptv[g] = tcur[g]; pdt[g] = dtv[g];
    act[g] = (tcur[g] < tfin[g]) && (dtv[g] > 0.f);
  }
#pragma unroll
  for (int l = 0; l < 2; ++l) { py[l] = y[l]; pf[l] = f[l]; ym[l] = y[l]; }

  // ---- adaptive stepping loop ----
  float k2[2], k3[2], k4v[2], k5[2], k6[2], k7[2], y1v[2];
  for (int iter = 0; iter < 4000; ++iter) {
    if (!(act[0] || act[1])) break;

#pragma unroll
    for (int l = 0; l < 2; ++l) yin[l] = y[l] + dtv[eh] * (SB10 * f[l]);
    drift(yin, k2);

#pragma unroll
    for (int l = 0; l < 2; ++l)
      yin[l] = y[l] + dtv[eh] * (SB20 * f[l] + SB21 * k2[l]);
    drift(yin, k3);

#pragma unroll
    for (int l = 0; l < 2; ++l)
      yin[l] = y[l] + dtv[eh] * (SB30 * f[l] + SB31 * k2[l] + SB32 * k3[l]);
    drift(yin, k4v);

#pragma unroll
    for (int l = 0; l < 2; ++l)
      yin[l] = y[l] + dtv[eh] * (SB40 * f[l] + SB41 * k2[l] + SB42 * k3[l] + SB43 * k4v[l]);
    drift(yin, k5);

#pragma unroll
    for (int l = 0; l < 2; ++l)
      yin[l] = y[l] + dtv[eh] * (SB50 * f[l] + SB51 * k2[l] + SB52 * k3[l] + SB53 * k4v[l] + SB54 * k5[l]);
    drift(yin, k6);

#pragma unroll
    for (int l = 0; l < 2; ++l)
      y1v[l] = y[l] + dtv[eh] * (CS0 * f[l] + CS2 * k3[l] + CS3 * k4v[l] + CS4 * k5[l] + CS5 * k6[l]);
    drift(y1v, k7);

    float rs[GE] = {0.f, 0.f};
#pragma unroll
    for (int l = 0; l < 2; ++l) {
      const float yerr = dtv[eh] * (CE0 * f[l] + CE2 * k3[l] + CE3 * k4v[l] + CE4 * k5[l] + CE5 * k6[l] + CE6 * k7[l]);
      const float tol = ATOL_C + RTOL_C * fmaxf(fabsf(y[l]), fabsf(y1v[l]));
      const float r = yerr / tol;
      rs[eh] += r * r;
    }
    float rsum[GE];
    blocksum(rs, rsum);

    bool acc[GE];
#pragma unroll
    for (int g = 0; g < GE; ++g)
      acc[g] = act[g] && (sqrtf(rsum[g] * (1.0f / Hd)) <= 1.0f);

    if (acc[eh]) {
#pragma unroll
      for (int l = 0; l < 2; ++l) {
        ym[l] = y[l] + dtv[eh] * (CM0 * f[l] + CM2 * k3[l] + CM3 * k4v[l] + CM4 * k5[l] + CM5 * k6[l] + CM6 * k7[l]);
        py[l] = y[l]; pf[l] = f[l];
        y[l] = y1v[l]; f[l] = k7[l];
      }
    }
#pragma unroll
    for (int g = 0; g < GE; ++g) {
      if (!act[g]) continue;
      const float er = sqrtf(rsum[g] * (1.0f / Hd));
      if (acc[g]) {
        ptv[g] = tcur[g]; pdt[g] = dtv[g];
        tcur[g] = tcur[g] + dtv[g];
      }
      float dtn;
      if (er == 0.0f) {
        dtn = dtv[g] * 10.0f;
      } else {
        const float dfac = (er < 1.0f) ? 1.0f : 0.2f;
        const float fac = fminf(10.0f, fmaxf(0.9f * powf(er, -0.2f), dfac));
        dtn = dtv[g] * fac;
      }
      dtv[g] = fmaxf(dtn, 0.0f);
      act[g] = (tcur[g] < tfin[g]) && (dtv[g] > 0.0f);
    }
  }

  // ---- interpolate at t_final (4th-order fit) and fused FC ----
  const float fcwA = fcW[jj];
  const float fcwB = fcW[j1];
  float s[GE] = {0.f, 0.f};
#pragma unroll
  for (int l = 0; l < 2; ++l) {
    const float denom = tcur[eh] - ptv[eh];
    const float xr = (tfin[eh] - ptv[eh]) / denom;
    const float dy0 = pdt[eh] * pf[l];
    const float dy1 = pdt[eh] * f[l];
    const float aa = -2.f * dy0 + 2.f * dy1 - 8.f * py[l] - 8.f * y[l] + 16.f * ym[l];
    const float bb =  5.f * dy0 - 3.f * dy1 + 18.f * py[l] + 14.f * y[l] - 32.f * ym[l];
    const float cc = -4.f * dy0 + 1.f * dy1 - 11.f * py[l] - 5.f * y[l] + 16.f * ym[l];
    const float dd = dy0;
    const float ee = py[l];
    const float yf = (((aa * xr + bb) * xr + cc) * xr + dd) * xr + ee;
    s[eh] += yf * ((l == 1) ? fcwB : fcwA);
  }
  float ssum[GE];
  blocksum(s, ssum);
  if (tid == 0) {
#pragma unroll
    for (int g = 0; g < GE; ++g) {
      float o = ssum[g] + fcb[0];
#pragma unroll
      for (int m = 0; m < MET; ++m) o += meta[(bg0 + g) * MET + m] * fcW[Hd + m];
      outp[bg0 + g] = o;
    }
  }
}

// ---------------- host launcher ----------------
extern "C" void kernel_launch(void* const* d_in, const int* in_sizes, int n_in,
                              void* d_out, int out_size, void* d_ws, size_t ws_size,
                              hipStream_t stream)
{
  (void)in_sizes; (void)n_in; (void)out_size; (void)ws_size;

  const float* x    = (const float*)d_in[0];
  const float* meta = (const float*)d_in[1];
  const float* eps  = (const float*)d_in[2];
  const float* gWih = (const float*)d_in[3];
  const float* gWhh = (const float*)d_in[4];
  const float* gbih = (const float*)d_in[5];
  const float* gbhh = (const float*)d_in[6];
  const float* eW1  = (const float*)d_in[7];
  const float* eb1  = (const float*)d_in[8];
  const float* eW2  = (const float*)d_in[9];
  const float* eb2  = (const float*)d_in[10];
  const float* oW1  = (const float*)d_in[11];
  const float* ob1  = (const float*)d_in[12];
  const float* oW2  = (const float*)d_in[13];
  const float* ob2  = (const float*)d_in[14];
  const float* fcW  = (const float*)d_in[15];
  const float* fcb  = (const float*)d_in[16];
  float* out = (float*)d_out;
  float* ws  = (float*)d_ws;

  // ws layout (floats)
  float* WhhP = ws + 0;          //  786432
  float* WihT = ws + 786432;     //   12288
  float* eW1P = ws + 798720;     //  262144
  float* eW2P = ws + 1060864;    //  524288
  float* oW1P = ws + 1585152;    //  262144
  float* oW2P = ws + 1847296;    //  262144
  float* hA   = ws + 2109440;    //  262144 (h ping / z0)
  float* hB   = ws + 2371584;    //  262144 (h pong / o1)

  // all 6 weight repacks in one launch (2109440 elements)
  pack_all_kernel<<<(2109440 + 255) / 256, 256, 0, stream>>>(
      gWhh, gWih, eW1, eW2, oW1, oW2, WhhP, WihT, eW1P, eW2P, oW1P, oW2P);
  hipMemsetAsync(hA, 0, (size_t)Bsz * Hd * sizeof(float), stream);

  // per-step GRU: 256 blocks x 256 threads, 4 rows/thread (min delivery)
  dim3 ggrid(32, 8);
  for (int t = 0; t < Nseq; ++t) {
    const float* hin = (t & 1) ? hB : hA;
    float* hout      = (t & 1) ? hA : hB;
    gru_step_kernel<<<ggrid, 256, 0, stream>>>(x, meta, WihT, WhhP, gbih, gbhh, hin, hout, t);
  }
  // final h in hA (t=63 odd writes hA)
  dim3 egrid(32, 8);
  gemm_relu_kernel<<<egrid, 256, 0, stream>>>(hA, eW1P, eb1, hB);           // o1 -> hB
  enc2_z0_kernel<<<egrid, 256, 0, stream>>>(hB, eW2P, eb2, eps, hA);        // z0 -> hA
  ode_fc_kernel<<<Bsz / 2, 512, 0, stream>>>(x, meta, hA, oW1P, ob1, oW2P, ob2, fcW, fcb, out);
}

// Round 10
// 4544.304 us; speedup vs baseline: 1.0011x; 1.0011x over previous
//
#include <hip/hip_runtime.h>
#include <math.h>

// Problem dims
constexpr int Bsz  = 512;
constexpr int Nseq = 64;
constexpr int DX   = 4;
constexpr int MET  = 4;
constexpr int Hd   = 512;
constexpr int H3d  = 1536;

constexpr float RTOL_C = 1e-3f;
constexpr float ATOL_C = 1e-5f;

// ---- Dopri5 tableau (exactly as in jax.experimental.ode, f64->f32) ----
constexpr float SB10 = (float)(1.0/5.0);
constexpr float SB20 = (float)(3.0/40.0),  SB21 = (float)(9.0/40.0);
constexpr float SB30 = (float)(44.0/45.0), SB31 = (float)(-56.0/15.0), SB32 = (float)(32.0/9.0);
constexpr float SB40 = (float)(19372.0/6561.0), SB41 = (float)(-25360.0/2187.0),
                SB42 = (float)(64448.0/6561.0), SB43 = (float)(-212.0/729.0);
constexpr float SB50 = (float)(9017.0/3168.0),  SB51 = (float)(-355.0/33.0),
                SB52 = (float)(46732.0/5247.0), SB53 = (float)(49.0/176.0),
                SB54 = (float)(-5103.0/18656.0);
constexpr float CS0 = (float)(35.0/384.0), CS2 = (float)(500.0/1113.0),
                CS3 = (float)(125.0/192.0), CS4 = (float)(-2187.0/6784.0),
                CS5 = (float)(11.0/84.0);
// Shampine error coefficients (c_sol - c_star), as written in jax ode.py
constexpr float CE0 = (float)(35.0/384.0 - 1951.0/21600.0);
constexpr float CE2 = (float)(500.0/1113.0 - 22642.0/50085.0);
constexpr float CE3 = (float)(125.0/192.0 - 451.0/720.0);
constexpr float CE4 = (float)(-2187.0/6784.0 + 12231.0/42400.0);
constexpr float CE5 = (float)(11.0/84.0 - 649.0/6300.0);
constexpr float CE6 = (float)(-1.0/60.0);
// dps_c_mid for interpolation fit
constexpr float CM0 = (float)(6025192743.0/30085553152.0/2.0);
constexpr float CM2 = (float)(51252292925.0/65400821598.0/2.0);
constexpr float CM3 = (float)(-2691868925.0/45128329728.0/2.0);
constexpr float CM4 = (float)(187940372067.0/1594534317056.0/2.0);
constexpr float CM5 = (float)(-1776094331.0/19743644256.0/2.0);
constexpr float CM6 = (float)(11237099.0/235043384.0/2.0);

__device__ __forceinline__ float selu_f(float v) {
  const float scl = 1.0507009873554805f;
  const float alp = 1.6732632423543772f;
  float e = v > 0.f ? v : alp * expm1f(v);
  return scl * e;
}
__device__ __forceinline__ float sigmoid_f(float v) {
  return 1.f / (1.f + expf(-v));
}

// ---------------- fused weight repack (one launch) ----------------
__global__ __launch_bounds__(256) void pack_all_kernel(
    const float* __restrict__ gWhh, const float* __restrict__ gWih,
    const float* __restrict__ eW1,  const float* __restrict__ eW2,
    const float* __restrict__ oW1,  const float* __restrict__ oW2,
    float* __restrict__ WhhP, float* __restrict__ WihT,
    float* __restrict__ eW1P, float* __restrict__ eW2P,
    float* __restrict__ oW1P, float* __restrict__ oW2P)
{
  int i = blockIdx.x * 256 + threadIdx.x;
  if (i < 786432) {
    const int r = i >> 9, k = i & 511;
    WhhP[(k >> 2) * (H3d * 4) + r * 4 + (k & 3)] = gWhh[i];
  } else if (i < 798720) {
    const int ii = i - 786432;
    const int r = ii >> 3, c = ii & 7;
    WihT[c * H3d + r] = gWih[ii];
  } else if (i < 1060864) {
    const int ii = i - 798720;
    const int r = ii >> 9, k = ii & 511;
    eW1P[(k >> 2) * (Hd * 4) + r * 4 + (k & 3)] = eW1[ii];
  } else if (i < 1585152) {
    const int ii = i - 1060864;
    const int r = ii >> 9, k = ii & 511;
    eW2P[(k >> 2) * (1024 * 4) + r * 4 + (k & 3)] = eW2[ii];
  } else if (i < 1847296) {
    const int ii = i - 1585152;
    const int r = ii >> 9, k = ii & 511;
    oW1P[(k >> 2) * (Hd * 4) + r * 4 + (k & 3)] = oW1[ii];
  } else if (i < 2109440) {
    const int ii = i - 1847296;
    const int r = ii >> 9, k = ii & 511;
    oW2P[(k >> 2) * (Hd * 4) + r * 4 + (k & 3)] = oW2[ii];
  }
}

// ---------------- GRU step: h_out = GRUCell(xm_t, h_in) ----------------
// grid (32,8) = 256 blocks (1/CU), 256 threads = 4 waves; wave rg owns rows
// 4rg..4rg+3 -> 4 rows/thread. Per-CU register-delivery per step:
// 4 waves x 384KB slice = 1.5MB (R6 was 3MB@26us, R8 was 6MB@45us -- time
// scales with delivered bytes at ~64B/cyc L1 return). Each weight float4 now
// feeds 12 FMAs. FMA floor 5.9us; delivery ~11.5us; predict ~13-16us/step.
// Per-(b,j) FMA chain identical to all prior rounds -> bit-identical h.
__global__ __launch_bounds__(256) void gru_step_kernel(
    const float* __restrict__ x, const float* __restrict__ meta,
    const float* __restrict__ WihT, const float* __restrict__ WhhP,
    const float* __restrict__ bih, const float* __restrict__ bhh,
    const float* __restrict__ h_in, float* __restrict__ h_out, int t)
{
  __shared__ __align__(16) float hs[16][Hd];     // 32 KB h tile
  const int tid = threadIdx.x;
  const int jl  = tid & 63;
  const int rg  = tid >> 6;                      // wave 0..3 -> rows 4rg..4rg+3
  const int j   = blockIdx.y * 64 + jl;
  const int b0  = blockIdx.x * 16;

  // stage 16x512 h tile (coalesced float4, 8 per thread)
  for (int i = tid; i < 16 * Hd / 4; i += 256)
    *(float4*)&hs[0][i * 4] = *(const float4*)&h_in[b0 * Hd + i * 4];
  __syncthreads();

  float ar[4] = {0.f, 0.f, 0.f, 0.f};
  float az[4] = {0.f, 0.f, 0.f, 0.f};
  float an[4] = {0.f, 0.f, 0.f, 0.f};
#pragma unroll 4
  for (int k4 = 0; k4 < Hd / 4; ++k4) {
    const float4 wr = *(const float4*)&WhhP[(k4 * H3d + j) * 4];
    const float4 wz = *(const float4*)&WhhP[(k4 * H3d + 512 + j) * 4];
    const float4 wn = *(const float4*)&WhhP[(k4 * H3d + 1024 + j) * 4];
#pragma unroll
    for (int m = 0; m < 4; ++m) {
      const float4 hv = *(const float4*)&hs[rg * 4 + m][k4 * 4];  // broadcast
      ar[m] += wr.x * hv.x + wr.y * hv.y + wr.z * hv.z + wr.w * hv.w;
      az[m] += wz.x * hv.x + wz.y * hv.y + wz.z * hv.z + wz.w * hv.w;
      an[m] += wn.x * hv.x + wn.y * hv.y + wn.z * hv.z + wn.w * hv.w;
    }
  }

  const float bihr = bih[j], bihz = bih[512 + j], bihn = bih[1024 + j];
  const float bhhr = bhh[j], bhhz = bhh[512 + j], bhhn = bhh[1024 + j];
  float wir[8], wiz[8], win[8];
#pragma unroll
  for (int kk = 0; kk < 8; ++kk) {
    wir[kk] = WihT[kk * H3d + j];
    wiz[kk] = WihT[kk * H3d + 512 + j];
    win[kk] = WihT[kk * H3d + 1024 + j];
  }

#pragma unroll
  for (int m = 0; m < 4; ++m) {
    const int bl = rg * 4 + m;
    const int b  = b0 + bl;
    const float4 xv = *(const float4*)&x[(b * Nseq + t) * DX];
    const float4 mv = *(const float4*)&meta[b * MET];
    float xm[8] = { xv.x, xv.y, xv.z, xv.w, mv.x, mv.y, mv.z, mv.w };
    float gr = bihr, gz = bihz, gn = bihn;
#pragma unroll
    for (int kk = 0; kk < 8; ++kk) {
      gr += xm[kk] * wir[kk];
      gz += xm[kk] * wiz[kk];
      gn += xm[kk] * win[kk];
    }
    const float r = sigmoid_f(gr + ar[m] + bhhr);
    const float z = sigmoid_f(gz + az[m] + bhhz);
    const float n = tanhf(gn + r * (an[m] + bhhn));
    const float hold = hs[bl][j];
    h_out[b * Hd + j] = (1.f - z) * n + z * hold;
  }
}

// ---------------- encoder layer 1: relu(A @ W^T + b) ----------------
__global__ __launch_bounds__(256) void gemm_relu_kernel(
    const float* __restrict__ A, const float* __restrict__ WP,
    const float* __restrict__ bias, float* __restrict__ Cout)
{
  __shared__ __align__(16) float as[16 * Hd];
  const int tid  = threadIdx.x;
  const int jl   = tid & 63;
  const int bsub = tid >> 6;
  const int j    = blockIdx.y * 64 + jl;
  const int b0   = blockIdx.x * 16;

  for (int i = tid; i < 16 * Hd; i += 256) as[i] = A[b0 * Hd + i];
  __syncthreads();

  float acc[4] = {0.f, 0.f, 0.f, 0.f};
#pragma unroll 2
  for (int k4 = 0; k4 < Hd / 4; ++k4) {
    const float4 w = *(const float4*)&WP[(k4 * Hd + j) * 4];
#pragma unroll
    for (int m = 0; m < 4; ++m) {
      const float4 av = *(const float4*)&as[(bsub * 4 + m) * Hd + k4 * 4];
      acc[m] += w.x * av.x + w.y * av.y + w.z * av.z + w.w * av.w;
    }
  }
  const float bj = bias[j];
#pragma unroll
  for (int m = 0; m < 4; ++m) {
    const int b = b0 + bsub * 4 + m;
    float v = acc[m] + bj;
    Cout[b * Hd + j] = v > 0.f ? v : 0.f;
  }
}

// ---------------- encoder layer 2 + reparam: z0 = eps*std + mean ----------------
__global__ __launch_bounds__(256) void enc2_z0_kernel(
    const float* __restrict__ O1, const float* __restrict__ W2P,  // [k4][1024][4]
    const float* __restrict__ b2, const float* __restrict__ eps,
    float* __restrict__ z0)
{
  __shared__ __align__(16) float as[16 * Hd];
  const int tid  = threadIdx.x;
  const int jl   = tid & 63;
  const int bsub = tid >> 6;
  const int j    = blockIdx.y * 64 + jl;
  const int b0   = blockIdx.x * 16;

  for (int i = tid; i < 16 * Hd; i += 256) as[i] = O1[b0 * Hd + i];
  __syncthreads();

  float am[4] = {0.f, 0.f, 0.f, 0.f};
  float asd[4] = {0.f, 0.f, 0.f, 0.f};
#pragma unroll 2
  for (int k4 = 0; k4 < Hd / 4; ++k4) {
    const float4 wm = *(const float4*)&W2P[(k4 * 1024 + j) * 4];
    const float4 ws = *(const float4*)&W2P[(k4 * 1024 + 512 + j) * 4];
#pragma unroll
    for (int m = 0; m < 4; ++m) {
      const float4 av = *(const float4*)&as[(bsub * 4 + m) * Hd + k4 * 4];
      am[m]  += wm.x * av.x + wm.y * av.y + wm.z * av.z + wm.w * av.w;
      asd[m] += ws.x * av.x + ws.y * av.y + ws.z * av.z + ws.w * av.w;
    }
  }
  const float bm = b2[j], bs = b2[512 + j];
#pragma unroll
  for (int m = 0; m < 4; ++m) {
    const int b = b0 + bsub * 4 + m;
    const float mean = am[m] + bm;
    const float sd   = asd[m] + bs;
    z0[b * Hd + j] = eps[b * Hd + j] * sd + mean;
  }
}

// ---------------- adaptive Dopri5 ODE solve + final FC ----------------
// 256 blocks x 512 threads, GE=2. Structural floor: each drift streams
// W1+W2 = 2MB through each CU's register path exactly once (no wave
// redundancy: each wave covers distinct j). ~11-12 lockstep iters x 6
// drifts x ~15us = the measured ~1070us.
__global__ __launch_bounds__(512) void ode_fc_kernel(
    const float* __restrict__ x, const float* __restrict__ meta,
    const float* __restrict__ z0in,
    const float* __restrict__ W1P, const float* __restrict__ b1v,
    const float* __restrict__ W2P, const float* __restrict__ b2v,
    const float* __restrict__ fcW, const float* __restrict__ fcb,
    float* __restrict__ outp)
{
  constexpr int GE = 2;
  __shared__ __align__(16) float zsh[GE][Hd];   // 4 KB
  __shared__ float red[8 * GE];
  const int tid = threadIdx.x;
  const int jj  = tid & 255;
  const int eh  = tid >> 8;            // element 0/1 (wave-uniform)
  const int j1  = jj + 256;
  const int bg0 = blockIdx.x * GE;

  const float b1a = b1v[jj], b1b = b1v[j1];
  const float b2a = b2v[jj], b2b = b2v[j1];

  // drift for the thread's 2 (j, eh) slots
  auto drift = [&](const float (&in)[2], float (&out)[2]) {
    __syncthreads();
    zsh[eh][jj] = in[0];
    zsh[eh][j1] = in[1];
    __syncthreads();
    float u0 = b1a, u1 = b1b;
#pragma unroll 4
    for (int k4 = 0; k4 < Hd / 4; ++k4) {
      const float4 wA = *(const float4*)&W1P[(k4 * Hd + jj) * 4];
      const float4 wB = *(const float4*)&W1P[(k4 * Hd + j1) * 4];
      const float4 z  = *(const float4*)&zsh[eh][k4 * 4];
      u0 += wA.x * z.x + wA.y * z.y + wA.z * z.z + wA.w * z.w;
      u1 += wB.x * z.x + wB.y * z.y + wB.z * z.z + wB.w * z.w;
    }
    u0 = selu_f(u0); u1 = selu_f(u1);
    __syncthreads();
    zsh[eh][jj] = u0;
    zsh[eh][j1] = u1;
    __syncthreads();
    float v0 = b2a, v1 = b2b;
#pragma unroll 4
    for (int k4 = 0; k4 < Hd / 4; ++k4) {
      const float4 wA = *(const float4*)&W2P[(k4 * Hd + jj) * 4];
      const float4 wB = *(const float4*)&W2P[(k4 * Hd + j1) * 4];
      const float4 z  = *(const float4*)&zsh[eh][k4 * 4];
      v0 += wA.x * z.x + wA.y * z.y + wA.z * z.z + wA.w * z.w;
      v1 += wB.x * z.x + wB.y * z.y + wB.z * z.z + wB.w * z.w;
    }
    out[0] = v0; out[1] = v1;
  };

  // block-wide per-element sum; all threads receive identical results
  auto blocksum = [&](float (&v)[GE], float (&s)[GE]) {
#pragma unroll
    for (int off = 32; off > 0; off >>= 1) {
#pragma unroll
      for (int g = 0; g < GE; ++g) v[g] += __shfl_down(v[g], off);
    }
    __syncthreads();
    if ((tid & 63) == 0) {
      const int w = tid >> 6;
#pragma unroll
      for (int g = 0; g < GE; ++g) red[w * GE + g] = v[g];
    }
    __syncthreads();
#pragma unroll
    for (int g = 0; g < GE; ++g) {
      float t = 0.f;
#pragma unroll
      for (int w = 0; w < 8; ++w) t += red[w * GE + g];
      s[g] = t;
    }
  };

  float y[2], f[2], py[2], pf[2], ym[2];
  float tcur[GE], dtv[GE], tfin[GE], ptv[GE], pdt[GE];
  bool act[GE];

  y[0] = z0in[(bg0 + eh) * Hd + jj];
  y[1] = z0in[(bg0 + eh) * Hd + j1];
#pragma unroll
  for (int g = 0; g < GE; ++g) {
    tcur[g] = x[((bg0 + g) * Nseq + 0) * DX];
    tfin[g] = x[((bg0 + g) * Nseq + (Nseq - 1)) * DX];
  }

  drift(y, f);

  // ---- initial step size (Hairer / jax variant) ----
  float sc[2];
  float q0[GE] = {0.f, 0.f}, q1[GE] = {0.f, 0.f};
#pragma unroll
  for (int l = 0; l < 2; ++l) {
    sc[l] = ATOL_C + RTOL_C * fabsf(y[l]);
    const float a = y[l] / sc[l], b = f[l] / sc[l];
    q0[eh] += a * a;
    q1[eh] += b * b;
  }
  float d0s[GE], d1s[GE];
  blocksum(q0, d0s);
  blocksum(q1, d1s);
  float h0[GE];
#pragma unroll
  for (int g = 0; g < GE; ++g) {
    const float d0 = sqrtf(d0s[g]), d1 = sqrtf(d1s[g]);
    h0[g] = (d0 < 1e-5f || d1 < 1e-5f) ? 1e-6f : 0.01f * d0 / d1;
  }
  float yin[2], f1h[2];
#pragma unroll
  for (int l = 0; l < 2; ++l) yin[l] = y[l] + h0[eh] * f[l];
  drift(yin, f1h);
  float q2[GE] = {0.f, 0.f};
#pragma unroll
  for (int l = 0; l < 2; ++l) {
    const float dd = (f1h[l] - f[l]) / sc[l];
    q2[eh] += dd * dd;
  }
  float d2s[GE];
  blocksum(q2, d2s);
#pragma unroll
  for (int g = 0; g < GE; ++g) {
    const float d1 = sqrtf(d1s[g]);
    const float d2 = sqrtf(d2s[g]) / h0[g];
    const float h1 = (d1 <= 1e-15f && d2 <= 1e-15f)
                 ? fmaxf(1e-6f, h0[g] * 1e-3f)
                 : powf(0.01f / (d1 + d2), 0.2f);   // jax uses d1+d2 here
    dtv[g] = fminf(100.f * h0[g], h1);
    ptv[g] = tcur[g]; pdt[g] = dtv[g];
    act[g] = (tcur[g] < tfin[g]) && (dtv[g] > 0.f);
  }
#pragma unroll
  for (int l = 0; l < 2; ++l) { py[l] = y[l]; pf[l] = f[l]; ym[l] = y[l]; }

  // ---- adaptive stepping loop ----
  float k2[2], k3[2], k4v[2], k5[2], k6[2], k7[2], y1v[2];
  for (int iter = 0; iter < 4000; ++iter) {
    if (!(act[0] || act[1])) break;

#pragma unroll
    for (int l = 0; l < 2; ++l) yin[l] = y[l] + dtv[eh] * (SB10 * f[l]);
    drift(yin, k2);

#pragma unroll
    for (int l = 0; l < 2; ++l)
      yin[l] = y[l] + dtv[eh] * (SB20 * f[l] + SB21 * k2[l]);
    drift(yin, k3);

#pragma unroll
    for (int l = 0; l < 2; ++l)
      yin[l] = y[l] + dtv[eh] * (SB30 * f[l] + SB31 * k2[l] + SB32 * k3[l]);
    drift(yin, k4v);

#pragma unroll
    for (int l = 0; l < 2; ++l)
      yin[l] = y[l] + dtv[eh] * (SB40 * f[l] + SB41 * k2[l] + SB42 * k3[l] + SB43 * k4v[l]);
    drift(yin, k5);

#pragma unroll
    for (int l = 0; l < 2; ++l)
      yin[l] = y[l] + dtv[eh] * (SB50 * f[l] + SB51 * k2[l] + SB52 * k3[l] + SB53 * k4v[l] + SB54 * k5[l]);
    drift(yin, k6);

#pragma unroll
    for (int l = 0; l < 2; ++l)
      y1v[l] = y[l] + dtv[eh] * (CS0 * f[l] + CS2 * k3[l] + CS3 * k4v[l] + CS4 * k5[l] + CS5 * k6[l]);
    drift(y1v, k7);

    float rs[GE] = {0.f, 0.f};
#pragma unroll
    for (int l = 0; l < 2; ++l) {
      const float yerr = dtv[eh] * (CE0 * f[l] + CE2 * k3[l] + CE3 * k4v[l] + CE4 * k5[l] + CE5 * k6[l] + CE6 * k7[l]);
      const float tol = ATOL_C + RTOL_C * fmaxf(fabsf(y[l]), fabsf(y1v[l]));
      const float r = yerr / tol;
      rs[eh] += r * r;
    }
    float rsum[GE];
    blocksum(rs, rsum);

    bool acc[GE];
#pragma unroll
    for (int g = 0; g < GE; ++g)
      acc[g] = act[g] && (sqrtf(rsum[g] * (1.0f / Hd)) <= 1.0f);

    if (acc[eh]) {
#pragma unroll
      for (int l = 0; l < 2; ++l) {
        ym[l] = y[l] + dtv[eh] * (CM0 * f[l] + CM2 * k3[l] + CM3 * k4v[l] + CM4 * k5[l] + CM5 * k6[l] + CM6 * k7[l]);
        py[l] = y[l]; pf[l] = f[l];
        y[l] = y1v[l]; f[l] = k7[l];
      }
    }
#pragma unroll
    for (int g = 0; g < GE; ++g) {
      if (!act[g]) continue;
      const float er = sqrtf(rsum[g] * (1.0f / Hd));
      if (acc[g]) {
        ptv[g] = tcur[g]; pdt[g] = dtv[g];
        tcur[g] = tcur[g] + dtv[g];
      }
      float dtn;
      if (er == 0.0f) {
        dtn = dtv[g] * 10.0f;
      } else {
        const float dfac = (er < 1.0f) ? 1.0f : 0.2f;
        const float fac = fminf(10.0f, fmaxf(0.9f * powf(er, -0.2f), dfac));
        dtn = dtv[g] * fac;
      }
      dtv[g] = fmaxf(dtn, 0.0f);
      act[g] = (tcur[g] < tfin[g]) && (dtv[g] > 0.0f);
    }
  }

  // ---- interpolate at t_final (4th-order fit) and fused FC ----
  const float fcwA = fcW[jj];
  const float fcwB = fcW[j1];
  float s[GE] = {0.f, 0.f};
#pragma unroll
  for (int l = 0; l < 2; ++l) {
    const float denom = tcur[eh] - ptv[eh];
    const float xr = (tfin[eh] - ptv[eh]) / denom;
    const float dy0 = pdt[eh] * pf[l];
    const float dy1 = pdt[eh] * f[l];
    const float aa = -2.f * dy0 + 2.f * dy1 - 8.f * py[l] - 8.f * y[l] + 16.f * ym[l];
    const float bb =  5.f * dy0 - 3.f * dy1 + 18.f * py[l] + 14.f * y[l] - 32.f * ym[l];
    const float cc = -4.f * dy0 + 1.f * dy1 - 11.f * py[l] - 5.f * y[l] + 16.f * ym[l];
    const float dd = dy0;
    const float ee = py[l];
    const float yf = (((aa * xr + bb) * xr + cc) * xr + dd) * xr + ee;
    s[eh] += yf * ((l == 1) ? fcwB : fcwA);
  }
  float ssum[GE];
  blocksum(s, ssum);
  if (tid == 0) {
#pragma unroll
    for (int g = 0; g < GE; ++g) {
      float o = ssum[g] + fcb[0];
#pragma unroll
      for (int m = 0; m < MET; ++m) o += meta[(bg0 + g) * MET + m] * fcW[Hd + m];
      outp[bg0 + g] = o;
    }
  }
}

// ---------------- host launcher ----------------
extern "C" void kernel_launch(void* const* d_in, const int* in_sizes, int n_in,
                              void* d_out, int out_size, void* d_ws, size_t ws_size,
                              hipStream_t stream)
{
  (void)in_sizes; (void)n_in; (void)out_size; (void)ws_size;

  const float* x    = (const float*)d_in[0];
  const float* meta = (const float*)d_in[1];
  const float* eps  = (const float*)d_in[2];
  const float* gWih = (const float*)d_in[3];
  const float* gWhh = (const float*)d_in[4];
  const float* gbih = (const float*)d_in[5];
  const float* gbhh = (const float*)d_in[6];
  const float* eW1  = (const float*)d_in[7];
  const float* eb1  = (const float*)d_in[8];
  const float* eW2  = (const float*)d_in[9];
  const float* eb2  = (const float*)d_in[10];
  const float* oW1  = (const float*)d_in[11];
  const float* ob1  = (const float*)d_in[12];
  const float* oW2  = (const float*)d_in[13];
  const float* ob2  = (const float*)d_in[14];
  const float* fcW  = (const float*)d_in[15];
  const float* fcb  = (const float*)d_in[16];
  float* out = (float*)d_out;
  float* ws  = (float*)d_ws;

  // ws layout (floats)
  float* WhhP = ws + 0;          //  786432
  float* WihT = ws + 786432;     //   12288
  float* eW1P = ws + 798720;     //  262144
  float* eW2P = ws + 1060864;    //  524288
  float* oW1P = ws + 1585152;    //  262144
  float* oW2P = ws + 1847296;    //  262144
  float* hA   = ws + 2109440;    //  262144 (h ping / z0)
  float* hB   = ws + 2371584;    //  262144 (h pong / o1)

  // all 6 weight repacks in one launch (2109440 elements)
  pack_all_kernel<<<(2109440 + 255) / 256, 256, 0, stream>>>(
      gWhh, gWih, eW1, eW2, oW1, oW2, WhhP, WihT, eW1P, eW2P, oW1P, oW2P);
  hipMemsetAsync(hA, 0, (size_t)Bsz * Hd * sizeof(float), stream);

  // per-step GRU: 256 blocks x 256 threads, 4 rows/thread (min delivery)
  dim3 ggrid(32, 8);
  for (int t = 0; t < Nseq; ++t) {
    const float* hin = (t & 1) ? hB : hA;
    float* hout      = (t & 1) ? hA : hB;
    gru_step_kernel<<<ggrid, 256, 0, stream>>>(x, meta, WihT, WhhP, gbih, gbhh, hin, hout, t);
  }
  // final h in hA (t=63 odd writes hA)
  dim3 egrid(32, 8);
  gemm_relu_kernel<<<egrid, 256, 0, stream>>>(hA, eW1P, eb1, hB);           // o1 -> hB
  enc2_z0_kernel<<<egrid, 256, 0, stream>>>(hB, eW2P, eb2, eps, hA);        // z0 -> hA
  ode_fc_kernel<<<Bsz / 2, 512, 0, stream>>>(x, meta, hA, oW1P, ob1, oW2P, ob2, fcW, fcb, out);
}

// Round 11
// 2862.795 us; speedup vs baseline: 1.5892x; 1.5874x over previous
//
#include <hip/hip_runtime.h>
#include <math.h>

// Problem dims
constexpr int Bsz  = 512;
constexpr int Nseq = 64;
constexpr int DX   = 4;
constexpr int MET  = 4;
constexpr int Hd   = 512;
constexpr int H3d  = 1536;

// Padded row count for L1 set de-aliasing: 520 rows -> gate stride 8320 B,
// k4 stride 24960 B (WhhP) / 8320 B (oW*P) -- not multiples of 8192, so the
// 3 gate streams + successive k4 lines no longer collide in one L1 set group.
constexpr int PJ = 520;

constexpr float RTOL_C = 1e-3f;
constexpr float ATOL_C = 1e-5f;

// ---- Dopri5 tableau (exactly as in jax.experimental.ode, f64->f32) ----
constexpr float SB10 = (float)(1.0/5.0);
constexpr float SB20 = (float)(3.0/40.0),  SB21 = (float)(9.0/40.0);
constexpr float SB30 = (float)(44.0/45.0), SB31 = (float)(-56.0/15.0), SB32 = (float)(32.0/9.0);
constexpr float SB40 = (float)(19372.0/6561.0), SB41 = (float)(-25360.0/2187.0),
                SB42 = (float)(64448.0/6561.0), SB43 = (float)(-212.0/729.0);
constexpr float SB50 = (float)(9017.0/3168.0),  SB51 = (float)(-355.0/33.0),
                SB52 = (float)(46732.0/5247.0), SB53 = (float)(49.0/176.0),
                SB54 = (float)(-5103.0/18656.0);
constexpr float CS0 = (float)(35.0/384.0), CS2 = (float)(500.0/1113.0),
                CS3 = (float)(125.0/192.0), CS4 = (float)(-2187.0/6784.0),
                CS5 = (float)(11.0/84.0);
// Shampine error coefficients (c_sol - c_star), as written in jax ode.py
constexpr float CE0 = (float)(35.0/384.0 - 1951.0/21600.0);
constexpr float CE2 = (float)(500.0/1113.0 - 22642.0/50085.0);
constexpr float CE3 = (float)(125.0/192.0 - 451.0/720.0);
constexpr float CE4 = (float)(-2187.0/6784.0 + 12231.0/42400.0);
constexpr float CE5 = (float)(11.0/84.0 - 649.0/6300.0);
constexpr float CE6 = (float)(-1.0/60.0);
// dps_c_mid for interpolation fit
constexpr float CM0 = (float)(6025192743.0/30085553152.0/2.0);
constexpr float CM2 = (float)(51252292925.0/65400821598.0/2.0);
constexpr float CM3 = (float)(-2691868925.0/45128329728.0/2.0);
constexpr float CM4 = (float)(187940372067.0/1594534317056.0/2.0);
constexpr float CM5 = (float)(-1776094331.0/19743644256.0/2.0);
constexpr float CM6 = (float)(11237099.0/235043384.0/2.0);

__device__ __forceinline__ float selu_f(float v) {
  const float scl = 1.0507009873554805f;
  const float alp = 1.6732632423543772f;
  float e = v > 0.f ? v : alp * expm1f(v);
  return scl * e;
}
__device__ __forceinline__ float sigmoid_f(float v) {
  return 1.f / (1.f + expf(-v));
}

// ---------------- fused weight repack (one launch) ----------------
// WhhP: [k4][gate][PJ][4]   (PJ=520 padded; only j<512 written/read)
// oW1P/oW2P: [k4][PJ][4]
// eW1P/eW2P: unpadded (encoder is ~2% of runtime)
__global__ __launch_bounds__(256) void pack_all_kernel(
    const float* __restrict__ gWhh, const float* __restrict__ gWih,
    const float* __restrict__ eW1,  const float* __restrict__ eW2,
    const float* __restrict__ oW1,  const float* __restrict__ oW2,
    float* __restrict__ WhhP, float* __restrict__ WihT,
    float* __restrict__ eW1P, float* __restrict__ eW2P,
    float* __restrict__ oW1P, float* __restrict__ oW2P)
{
  int i = blockIdx.x * 256 + threadIdx.x;
  if (i < 786432) {                       // gWhh (1536x512)
    const int r = i >> 9, k = i & 511;
    const int gate = r >> 9, jr = r & 511;
    WhhP[(((k >> 2) * 3 + gate) * PJ + jr) * 4 + (k & 3)] = gWhh[i];
  } else if (i < 798720) {                // gWih (1536x8) -> transpose
    const int ii = i - 786432;
    const int r = ii >> 3, c = ii & 7;
    WihT[c * H3d + r] = gWih[ii];
  } else if (i < 1060864) {               // eW1 (512x512)
    const int ii = i - 798720;
    const int r = ii >> 9, k = ii & 511;
    eW1P[(k >> 2) * (Hd * 4) + r * 4 + (k & 3)] = eW1[ii];
  } else if (i < 1585152) {               // eW2 (1024x512)
    const int ii = i - 1060864;
    const int r = ii >> 9, k = ii & 511;
    eW2P[(k >> 2) * (1024 * 4) + r * 4 + (k & 3)] = eW2[ii];
  } else if (i < 1847296) {               // oW1 (512x512), padded
    const int ii = i - 1585152;
    const int r = ii >> 9, k = ii & 511;
    oW1P[((k >> 2) * PJ + r) * 4 + (k & 3)] = oW1[ii];
  } else if (i < 2109440) {               // oW2 (512x512), padded
    const int ii = i - 1847296;
    const int r = ii >> 9, k = ii & 511;
    oW2P[((k >> 2) * PJ + r) * 4 + (k & 3)] = oW2[ii];
  }
}

// ---------------- GRU step: h_out = GRUCell(xm_t, h_in) ----------------
// Exact R6 shape (best measured: 26us/step): grid (32,8) = 256 blocks (1/CU),
// 512 threads = 8 waves (2/SIMD); wave rg owns rows 2rg, 2rg+1.
// NEW: padded weight layout de-aliases the 3 gate streams in L1 (R6's gate
// stride 8192 B == L1 set-group stride -> conflict misses; ODE kernel at
// 124 B/cyc vs GRU 63 B/cyc was the evidence). Arithmetic order unchanged.
__global__ __launch_bounds__(512) void gru_step_kernel(
    const float* __restrict__ x, const float* __restrict__ meta,
    const float* __restrict__ WihT, const float* __restrict__ WhhP,
    const float* __restrict__ bih, const float* __restrict__ bhh,
    const float* __restrict__ h_in, float* __restrict__ h_out, int t)
{
  __shared__ __align__(16) float hs[16 * Hd];    // 32 KB h tile
  const int tid = threadIdx.x;
  const int jl  = tid & 63;
  const int rg  = tid >> 6;                      // wave 0..7 -> rows 2rg, 2rg+1
  const int j   = blockIdx.y * 64 + jl;
  const int b0  = blockIdx.x * 16;

  // stage this block's 16x512 h tile into LDS (coalesced float4)
  for (int i = tid; i < 16 * Hd / 4; i += 512)
    *(float4*)&hs[i * 4] = *(const float4*)&h_in[b0 * Hd + i * 4];
  __syncthreads();

  float ar0 = 0.f, az0 = 0.f, an0 = 0.f;
  float ar1 = 0.f, az1 = 0.f, an1 = 0.f;
#pragma unroll 4
  for (int k4 = 0; k4 < Hd / 4; ++k4) {
    const float4 wr = *(const float4*)&WhhP[((k4 * 3 + 0) * PJ + j) * 4];
    const float4 wz = *(const float4*)&WhhP[((k4 * 3 + 1) * PJ + j) * 4];
    const float4 wn = *(const float4*)&WhhP[((k4 * 3 + 2) * PJ + j) * 4];
    const float4 h0 = *(const float4*)&hs[(rg * 2 + 0) * Hd + k4 * 4];  // broadcast
    const float4 h1 = *(const float4*)&hs[(rg * 2 + 1) * Hd + k4 * 4];
    ar0 += wr.x * h0.x + wr.y * h0.y + wr.z * h0.z + wr.w * h0.w;
    az0 += wz.x * h0.x + wz.y * h0.y + wz.z * h0.z + wz.w * h0.w;
    an0 += wn.x * h0.x + wn.y * h0.y + wn.z * h0.z + wn.w * h0.w;
    ar1 += wr.x * h1.x + wr.y * h1.y + wr.z * h1.z + wr.w * h1.w;
    az1 += wz.x * h1.x + wz.y * h1.y + wz.z * h1.z + wz.w * h1.w;
    an1 += wn.x * h1.x + wn.y * h1.y + wn.z * h1.z + wn.w * h1.w;
  }

  const float bihr = bih[j], bihz = bih[512 + j], bihn = bih[1024 + j];
  const float bhhr = bhh[j], bhhz = bhh[512 + j], bhhn = bhh[1024 + j];
  float wir[8], wiz[8], win[8];
#pragma unroll
  for (int kk = 0; kk < 8; ++kk) {
    wir[kk] = WihT[kk * H3d + j];
    wiz[kk] = WihT[kk * H3d + 512 + j];
    win[kk] = WihT[kk * H3d + 1024 + j];
  }

#pragma unroll
  for (int m = 0; m < 2; ++m) {
    const int bl = rg * 2 + m;
    const int b  = b0 + bl;
    const float4 xv = *(const float4*)&x[(b * Nseq + t) * DX];
    const float4 mv = *(const float4*)&meta[b * MET];
    float xm[8] = { xv.x, xv.y, xv.z, xv.w, mv.x, mv.y, mv.z, mv.w };
    float gr = bihr, gz = bihz, gn = bihn;
#pragma unroll
    for (int kk = 0; kk < 8; ++kk) {
      gr += xm[kk] * wir[kk];
      gz += xm[kk] * wiz[kk];
      gn += xm[kk] * win[kk];
    }
    const float ghr = (m ? ar1 : ar0) + bhhr;
    const float ghz = (m ? az1 : az0) + bhhz;
    const float ghn = (m ? an1 : an0) + bhhn;
    const float r = sigmoid_f(gr + ghr);
    const float z = sigmoid_f(gz + ghz);
    const float n = tanhf(gn + r * ghn);
    const float hold = hs[bl * Hd + j];
    h_out[b * Hd + j] = (1.f - z) * n + z * hold;
  }
}

// ---------------- encoder layer 1: relu(A @ W^T + b) ----------------
__global__ __launch_bounds__(256) void gemm_relu_kernel(
    const float* __restrict__ A, const float* __restrict__ WP,
    const float* __restrict__ bias, float* __restrict__ Cout)
{
  __shared__ __align__(16) float as[16 * Hd];
  const int tid  = threadIdx.x;
  const int jl   = tid & 63;
  const int bsub = tid >> 6;
  const int j    = blockIdx.y * 64 + jl;
  const int b0   = blockIdx.x * 16;

  for (int i = tid; i < 16 * Hd; i += 256) as[i] = A[b0 * Hd + i];
  __syncthreads();

  float acc[4] = {0.f, 0.f, 0.f, 0.f};
#pragma unroll 2
  for (int k4 = 0; k4 < Hd / 4; ++k4) {
    const float4 w = *(const float4*)&WP[(k4 * Hd + j) * 4];
#pragma unroll
    for (int m = 0; m < 4; ++m) {
      const float4 av = *(const float4*)&as[(bsub * 4 + m) * Hd + k4 * 4];
      acc[m] += w.x * av.x + w.y * av.y + w.z * av.z + w.w * av.w;
    }
  }
  const float bj = bias[j];
#pragma unroll
  for (int m = 0; m < 4; ++m) {
    const int b = b0 + bsub * 4 + m;
    float v = acc[m] + bj;
    Cout[b * Hd + j] = v > 0.f ? v : 0.f;
  }
}

// ---------------- encoder layer 2 + reparam: z0 = eps*std + mean ----------------
__global__ __launch_bounds__(256) void enc2_z0_kernel(
    const float* __restrict__ O1, const float* __restrict__ W2P,  // [k4][1024][4]
    const float* __restrict__ b2, const float* __restrict__ eps,
    float* __restrict__ z0)
{
  __shared__ __align__(16) float as[16 * Hd];
  const int tid  = threadIdx.x;
  const int jl   = tid & 63;
  const int bsub = tid >> 6;
  const int j    = blockIdx.y * 64 + jl;
  const int b0   = blockIdx.x * 16;

  for (int i = tid; i < 16 * Hd; i += 256) as[i] = O1[b0 * Hd + i];
  __syncthreads();

  float am[4] = {0.f, 0.f, 0.f, 0.f};
  float asd[4] = {0.f, 0.f, 0.f, 0.f};
#pragma unroll 2
  for (int k4 = 0; k4 < Hd / 4; ++k4) {
    const float4 wm = *(const float4*)&W2P[(k4 * 1024 + j) * 4];
    const float4 ws = *(const float4*)&W2P[(k4 * 1024 + 512 + j) * 4];
#pragma unroll
    for (int m = 0; m < 4; ++m) {
      const float4 av = *(const float4*)&as[(bsub * 4 + m) * Hd + k4 * 4];
      am[m]  += wm.x * av.x + wm.y * av.y + wm.z * av.z + wm.w * av.w;
      asd[m] += ws.x * av.x + ws.y * av.y + ws.z * av.z + ws.w * av.w;
    }
  }
  const float bm = b2[j], bs = b2[512 + j];
#pragma unroll
  for (int m = 0; m < 4; ++m) {
    const int b = b0 + bsub * 4 + m;
    const float mean = am[m] + bm;
    const float sd   = asd[m] + bs;
    z0[b * Hd + j] = eps[b * Hd + j] * sd + mean;
  }
}

// ---------------- adaptive Dopri5 ODE solve + final FC ----------------
// 256 blocks x 512 threads, GE=2. Weight layout padded (PJ=520) so the
// k4 stream stride is 8320 B, not 8192 -> no L1 set aliasing.
__global__ __launch_bounds__(512) void ode_fc_kernel(
    const float* __restrict__ x, const float* __restrict__ meta,
    const float* __restrict__ z0in,
    const float* __restrict__ W1P, const float* __restrict__ b1v,
    const float* __restrict__ W2P, const float* __restrict__ b2v,
    const float* __restrict__ fcW, const float* __restrict__ fcb,
    float* __restrict__ outp)
{
  constexpr int GE = 2;
  __shared__ __align__(16) float zsh[GE][Hd];   // 4 KB
  __shared__ float red[8 * GE];
  const int tid = threadIdx.x;
  const int jj  = tid & 255;
  const int eh  = tid >> 8;            // element 0/1 (wave-uniform)
  const int j1  = jj + 256;
  const int bg0 = blockIdx.x * GE;

  const float b1a = b1v[jj], b1b = b1v[j1];
  const float b2a = b2v[jj], b2b = b2v[j1];

  // drift for the thread's 2 (j, eh) slots
  auto drift = [&](const float (&in)[2], float (&out)[2]) {
    __syncthreads();
    zsh[eh][jj] = in[0];
    zsh[eh][j1] = in[1];
    __syncthreads();
    float u0 = b1a, u1 = b1b;
#pragma unroll 4
    for (int k4 = 0; k4 < Hd / 4; ++k4) {
      const float4 wA = *(const float4*)&W1P[(k4 * PJ + jj) * 4];
      const float4 wB = *(const float4*)&W1P[(k4 * PJ + j1) * 4];
      const float4 z  = *(const float4*)&zsh[eh][k4 * 4];
      u0 += wA.x * z.x + wA.y * z.y + wA.z * z.z + wA.w * z.w;
      u1 += wB.x * z.x + wB.y * z.y + wB.z * z.z + wB.w * z.w;
    }
    u0 = selu_f(u0); u1 = selu_f(u1);
    __syncthreads();
    zsh[eh][jj] = u0;
    zsh[eh][j1] = u1;
    __syncthreads();
    float v0 = b2a, v1 = b2b;
#pragma unroll 4
    for (int k4 = 0; k4 < Hd / 4; ++k4) {
      const float4 wA = *(const float4*)&W2P[(k4 * PJ + jj) * 4];
      const float4 wB = *(const float4*)&W2P[(k4 * PJ + j1) * 4];
      const float4 z  = *(const float4*)&zsh[eh][k4 * 4];
      v0 += wA.x * z.x + wA.y * z.y + wA.z * z.z + wA.w * z.w;
      v1 += wB.x * z.x + wB.y * z.y + wB.z * z.z + wB.w * z.w;
    }
    out[0] = v0; out[1] = v1;
  };

  // block-wide per-element sum; all threads receive identical results
  auto blocksum = [&](float (&v)[GE], float (&s)[GE]) {
#pragma unroll
    for (int off = 32; off > 0; off >>= 1) {
#pragma unroll
      for (int g = 0; g < GE; ++g) v[g] += __shfl_down(v[g], off);
    }
    __syncthreads();
    if ((tid & 63) == 0) {
      const int w = tid >> 6;
#pragma unroll
      for (int g = 0; g < GE; ++g) red[w * GE + g] = v[g];
    }
    __syncthreads();
#pragma unroll
    for (int g = 0; g < GE; ++g) {
      float t = 0.f;
#pragma unroll
      for (int w = 0; w < 8; ++w) t += red[w * GE + g];
      s[g] = t;
    }
  };

  float y[2], f[2], py[2], pf[2], ym[2];
  float tcur[GE], dtv[GE], tfin[GE], ptv[GE], pdt[GE];
  bool act[GE];

  y[0] = z0in[(bg0 + eh) * Hd + jj];
  y[1] = z0in[(bg0 + eh) * Hd + j1];
#pragma unroll
  for (int g = 0; g < GE; ++g) {
    tcur[g] = x[((bg0 + g) * Nseq + 0) * DX];
    tfin[g] = x[((bg0 + g) * Nseq + (Nseq - 1)) * DX];
  }

  drift(y, f);

  // ---- initial step size (Hairer / jax variant) ----
  float sc[2];
  float q0[GE] = {0.f, 0.f}, q1[GE] = {0.f, 0.f};
#pragma unroll
  for (int l = 0; l < 2; ++l) {
    sc[l] = ATOL_C + RTOL_C * fabsf(y[l]);
    const float a = y[l] / sc[l], b = f[l] / sc[l];
    q0[eh] += a * a;
    q1[eh] += b * b;
  }
  float d0s[GE], d1s[GE];
  blocksum(q0, d0s);
  blocksum(q1, d1s);
  float h0[GE];
#pragma unroll
  for (int g = 0; g < GE; ++g) {
    const float d0 = sqrtf(d0s[g]), d1 = sqrtf(d1s[g]);
    h0[g] = (d0 < 1e-5f || d1 < 1e-5f) ? 1e-6f : 0.01f * d0 / d1;
  }
  float yin[2], f1h[2];
#pragma unroll
  for (int l = 0; l < 2; ++l) yin[l] = y[l] + h0[eh] * f[l];
  drift(yin, f1h);
  float q2[GE] = {0.f, 0.f};
#pragma unroll
  for (int l = 0; l < 2; ++l) {
    const float dd = (f1h[l] - f[l]) / sc[l];
    q2[eh] += dd * dd;
  }
  float d2s[GE];
  blocksum(q2, d2s);
#pragma unroll
  for (int g = 0; g < GE; ++g) {
    const float d1 = sqrtf(d1s[g]);
    const float d2 = sqrtf(d2s[g]) / h0[g];
    const float h1 = (d1 <= 1e-15f && d2 <= 1e-15f)
                 ? fmaxf(1e-6f, h0[g] * 1e-3f)
                 : powf(0.01f / (d1 + d2), 0.2f);   // jax uses d1+d2 here
    dtv[g] = fminf(100.f * h0[g], h1);
    ptv[g] = tcur[g]; pdt[g] = dtv[g];
    act[g] = (tcur[g] < tfin[g]) && (dtv[g] > 0.f);
  }
#pragma unroll
  for (int l = 0; l < 2; ++l) { py[l] = y[l]; pf[l] = f[l]; ym[l] = y[l]; }

  // ---- adaptive stepping loop ----
  float k2[2], k3[2], k4v[2], k5[2], k6[2], k7[2], y1v[2];
  for (int iter = 0; iter < 4000; ++iter) {
    if (!(act[0] || act[1])) break;

#pragma unroll
    for (int l = 0; l < 2; ++l) yin[l] = y[l] + dtv[eh] * (SB10 * f[l]);
    drift(yin, k2);

#pragma unroll
    for (int l = 0; l < 2; ++l)
      yin[l] = y[l] + dtv[eh] * (SB20 * f[l] + SB21 * k2[l]);
    drift(yin, k3);

#pragma unroll
    for (int l = 0; l < 2; ++l)
      yin[l] = y[l] + dtv[eh] * (SB30 * f[l] + SB31 * k2[l] + SB32 * k3[l]);
    drift(yin, k4v);

#pragma unroll
    for (int l = 0; l < 2; ++l)
      yin[l] = y[l] + dtv[eh] * (SB40 * f[l] + SB41 * k2[l] + SB42 * k3[l] + SB43 * k4v[l]);
    drift(yin, k5);

#pragma unroll
    for (int l = 0; l < 2; ++l)
      yin[l] = y[l] + dtv[eh] * (SB50 * f[l] + SB51 * k2[l] + SB52 * k3[l] + SB53 * k4v[l] + SB54 * k5[l]);
    drift(yin, k6);

#pragma unroll
    for (int l = 0; l < 2; ++l)
      y1v[l] = y[l] + dtv[eh] * (CS0 * f[l] + CS2 * k3[l] + CS3 * k4v[l] + CS4 * k5[l] + CS5 * k6[l]);
    drift(y1v, k7);

    float rs[GE] = {0.f, 0.f};
#pragma unroll
    for (int l = 0; l < 2; ++l) {
      const float yerr = dtv[eh] * (CE0 * f[l] + CE2 * k3[l] + CE3 * k4v[l] + CE4 * k5[l] + CE5 * k6[l] + CE6 * k7[l]);
      const float tol = ATOL_C + RTOL_C * fmaxf(fabsf(y[l]), fabsf(y1v[l]));
      const float r = yerr / tol;
      rs[eh] += r * r;
    }
    float rsum[GE];
    blocksum(rs, rsum);

    bool acc[GE];
#pragma unroll
    for (int g = 0; g < GE; ++g)
      acc[g] = act[g] && (sqrtf(rsum[g] * (1.0f / Hd)) <= 1.0f);

    if (acc[eh]) {
#pragma unroll
      for (int l = 0; l < 2; ++l) {
        ym[l] = y[l] + dtv[eh] * (CM0 * f[l] + CM2 * k3[l] + CM3 * k4v[l] + CM4 * k5[l] + CM5 * k6[l] + CM6 * k7[l]);
        py[l] = y[l]; pf[l] = f[l];
        y[l] = y1v[l]; f[l] = k7[l];
      }
    }
#pragma unroll
    for (int g = 0; g < GE; ++g) {
      if (!act[g]) continue;
      const float er = sqrtf(rsum[g] * (1.0f / Hd));
      if (acc[g]) {
        ptv[g] = tcur[g]; pdt[g] = dtv[g];
        tcur[g] = tcur[g] + dtv[g];
      }
      float dtn;
      if (er == 0.0f) {
        dtn = dtv[g] * 10.0f;
      } else {
        const float dfac = (er < 1.0f) ? 1.0f : 0.2f;
        const float fac = fminf(10.0f, fmaxf(0.9f * powf(er, -0.2f), dfac));
        dtn = dtv[g] * fac;
      }
      dtv[g] = fmaxf(dtn, 0.0f);
      act[g] = (tcur[g] < tfin[g]) && (dtv[g] > 0.0f);
    }
  }

  // ---- interpolate at t_final (4th-order fit) and fused FC ----
  const float fcwA = fcW[jj];
  const float fcwB = fcW[j1];
  float s[GE] = {0.f, 0.f};
#pragma unroll
  for (int l = 0; l < 2; ++l) {
    const float denom = tcur[eh] - ptv[eh];
    const float xr = (tfin[eh] - ptv[eh]) / denom;
    const float dy0 = pdt[eh] * pf[l];
    const float dy1 = pdt[eh] * f[l];
    const float aa = -2.f * dy0 + 2.f * dy1 - 8.f * py[l] - 8.f * y[l] + 16.f * ym[l];
    const float bb =  5.f * dy0 - 3.f * dy1 + 18.f * py[l] + 14.f * y[l] - 32.f * ym[l];
    const float cc = -4.f * dy0 + 1.f * dy1 - 11.f * py[l] - 5.f * y[l] + 16.f * ym[l];
    const float dd = dy0;
    const float ee = py[l];
    const float yf = (((aa * xr + bb) * xr + cc) * xr + dd) * xr + ee;
    s[eh] += yf * ((l == 1) ? fcwB : fcwA);
  }
  float ssum[GE];
  blocksum(s, ssum);
  if (tid == 0) {
#pragma unroll
    for (int g = 0; g < GE; ++g) {
      float o = ssum[g] + fcb[0];
#pragma unroll
      for (int m = 0; m < MET; ++m) o += meta[(bg0 + g) * MET + m] * fcW[Hd + m];
      outp[bg0 + g] = o;
    }
  }
}

// ---------------- host launcher ----------------
extern "C" void kernel_launch(void* const* d_in, const int* in_sizes, int n_in,
                              void* d_out, int out_size, void* d_ws, size_t ws_size,
                              hipStream_t stream)
{
  (void)in_sizes; (void)n_in; (void)out_size; (void)ws_size;

  const float* x    = (const float*)d_in[0];
  const float* meta = (const float*)d_in[1];
  const float* eps  = (const float*)d_in[2];
  const float* gWih = (const float*)d_in[3];
  const float* gWhh = (const float*)d_in[4];
  const float* gbih = (const float*)d_in[5];
  const float* gbhh = (const float*)d_in[6];
  const float* eW1  = (const float*)d_in[7];
  const float* eb1  = (const float*)d_in[8];
  const float* eW2  = (const float*)d_in[9];
  const float* eb2  = (const float*)d_in[10];
  const float* oW1  = (const float*)d_in[11];
  const float* ob1  = (const float*)d_in[12];
  const float* oW2  = (const float*)d_in[13];
  const float* ob2  = (const float*)d_in[14];
  const float* fcW  = (const float*)d_in[15];
  const float* fcb  = (const float*)d_in[16];
  float* out = (float*)d_out;
  float* ws  = (float*)d_ws;

  // ws layout (floats), padded weight buffers
  float* WhhP = ws + 0;          // 128*3*520*4 = 798720
  float* WihT = ws + 798720;     //   12288
  float* eW1P = ws + 811008;     //  262144
  float* eW2P = ws + 1073152;    //  524288
  float* oW1P = ws + 1597440;    // 128*520*4 = 266240
  float* oW2P = ws + 1863680;    //  266240
  float* hA   = ws + 2129920;    //  262144 (h ping / z0)
  float* hB   = ws + 2392064;    //  262144 (h pong / o1)

  // all 6 weight repacks in one launch (2109440 input elements)
  pack_all_kernel<<<(2109440 + 255) / 256, 256, 0, stream>>>(
      gWhh, gWih, eW1, eW2, oW1, oW2, WhhP, WihT, eW1P, eW2P, oW1P, oW2P);
  hipMemsetAsync(hA, 0, (size_t)Bsz * Hd * sizeof(float), stream);

  // per-step GRU: 256 blocks x 512 threads (R6 shape, padded weights)
  dim3 ggrid(32, 8);
  for (int t = 0; t < Nseq; ++t) {
    const float* hin = (t & 1) ? hB : hA;
    float* hout      = (t & 1) ? hA : hB;
    gru_step_kernel<<<ggrid, 512, 0, stream>>>(x, meta, WihT, WhhP, gbih, gbhh, hin, hout, t);
  }
  // final h in hA (t=63 odd writes hA)
  dim3 egrid(32, 8);
  gemm_relu_kernel<<<egrid, 256, 0, stream>>>(hA, eW1P, eb1, hB);           // o1 -> hB
  enc2_z0_kernel<<<egrid, 256, 0, stream>>>(hB, eW2P, eb2, eps, hA);        // z0 -> hA
  ode_fc_kernel<<<Bsz / 2, 512, 0, stream>>>(x, meta, hA, oW1P, ob1, oW2P, ob2, fcW, fcb, out);
}

// Round 12
// 2751.753 us; speedup vs baseline: 1.6533x; 1.0404x over previous
//
#include <hip/hip_runtime.h>
#include <math.h>

// Problem dims
constexpr int Bsz  = 512;
constexpr int Nseq = 64;
constexpr int DX   = 4;
constexpr int MET  = 4;
constexpr int Hd   = 512;
constexpr int H3d  = 1536;

constexpr int PJ = 520;     // padded j-rows in packed weights (kept from R11)
constexpr int CK = 8;       // k4 per staged GRU chunk (chunk = CK*2 gates*64j*16B = 16 KB)

constexpr float RTOL_C = 1e-3f;
constexpr float ATOL_C = 1e-5f;

// ---- Dopri5 tableau (exactly as in jax.experimental.ode, f64->f32) ----
constexpr float SB10 = (float)(1.0/5.0);
constexpr float SB20 = (float)(3.0/40.0),  SB21 = (float)(9.0/40.0);
constexpr float SB30 = (float)(44.0/45.0), SB31 = (float)(-56.0/15.0), SB32 = (float)(32.0/9.0);
constexpr float SB40 = (float)(19372.0/6561.0), SB41 = (float)(-25360.0/2187.0),
                SB42 = (float)(64448.0/6561.0), SB43 = (float)(-212.0/729.0);
constexpr float SB50 = (float)(9017.0/3168.0),  SB51 = (float)(-355.0/33.0),
                SB52 = (float)(46732.0/5247.0), SB53 = (float)(49.0/176.0),
                SB54 = (float)(-5103.0/18656.0);
constexpr float CS0 = (float)(35.0/384.0), CS2 = (float)(500.0/1113.0),
                CS3 = (float)(125.0/192.0), CS4 = (float)(-2187.0/6784.0),
                CS5 = (float)(11.0/84.0);
// Shampine error coefficients (c_sol - c_star), as written in jax ode.py
constexpr float CE0 = (float)(35.0/384.0 - 1951.0/21600.0);
constexpr float CE2 = (float)(500.0/1113.0 - 22642.0/50085.0);
constexpr float CE3 = (float)(125.0/192.0 - 451.0/720.0);
constexpr float CE4 = (float)(-2187.0/6784.0 + 12231.0/42400.0);
constexpr float CE5 = (float)(11.0/84.0 - 649.0/6300.0);
constexpr float CE6 = (float)(-1.0/60.0);
// dps_c_mid for interpolation fit
constexpr float CM0 = (float)(6025192743.0/30085553152.0/2.0);
constexpr float CM2 = (float)(51252292925.0/65400821598.0/2.0);
constexpr float CM3 = (float)(-2691868925.0/45128329728.0/2.0);
constexpr float CM4 = (float)(187940372067.0/1594534317056.0/2.0);
constexpr float CM5 = (float)(-1776094331.0/19743644256.0/2.0);
constexpr float CM6 = (float)(11237099.0/235043384.0/2.0);

__device__ __forceinline__ float selu_f(float v) {
  const float scl = 1.0507009873554805f;
  const float alp = 1.6732632423543772f;
  float e = v > 0.f ? v : alp * expm1f(v);
  return scl * e;
}
__device__ __forceinline__ float sigmoid_f(float v) {
  return 1.f / (1.f + expf(-v));
}

// ---------------- fused weight repack (one launch, padded layouts) ----------------
// WhhP: [k4][gate][PJ][4] ; oW1P/oW2P: [k4][PJ][4] ; eW*P unpadded.
__global__ __launch_bounds__(256) void pack_all_kernel(
    const float* __restrict__ gWhh, const float* __restrict__ gWih,
    const float* __restrict__ eW1,  const float* __restrict__ eW2,
    const float* __restrict__ oW1,  const float* __restrict__ oW2,
    float* __restrict__ WhhP, float* __restrict__ WihT,
    float* __restrict__ eW1P, float* __restrict__ eW2P,
    float* __restrict__ oW1P, float* __restrict__ oW2P)
{
  int i = blockIdx.x * 256 + threadIdx.x;
  if (i < 786432) {                       // gWhh (1536x512)
    const int r = i >> 9, k = i & 511;
    const int gate = r >> 9, jr = r & 511;
    WhhP[(((k >> 2) * 3 + gate) * PJ + jr) * 4 + (k & 3)] = gWhh[i];
  } else if (i < 798720) {                // gWih (1536x8) -> transpose
    const int ii = i - 786432;
    const int r = ii >> 3, c = ii & 7;
    WihT[c * H3d + r] = gWih[ii];
  } else if (i < 1060864) {               // eW1 (512x512)
    const int ii = i - 798720;
    const int r = ii >> 9, k = ii & 511;
    eW1P[(k >> 2) * (Hd * 4) + r * 4 + (k & 3)] = eW1[ii];
  } else if (i < 1585152) {               // eW2 (1024x512)
    const int ii = i - 1060864;
    const int r = ii >> 9, k = ii & 511;
    eW2P[(k >> 2) * (1024 * 4) + r * 4 + (k & 3)] = eW2[ii];
  } else if (i < 1847296) {               // oW1 (512x512), padded
    const int ii = i - 1585152;
    const int r = ii >> 9, k = ii & 511;
    oW1P[((k >> 2) * PJ + r) * 4 + (k & 3)] = oW1[ii];
  } else if (i < 2109440) {               // oW2 (512x512), padded
    const int ii = i - 1847296;
    const int r = ii >> 9, k = ii & 511;
    oW2P[((k >> 2) * PJ + r) * 4 + (k & 3)] = oW2[ii];
  }
}

// ---------------- GRU step: h_out = GRUCell(xm_t, h_in) ----------------
// R6 shape (grid (32,8), 512 thr, 8 waves, wave rg -> rows 2rg,2rg+1) with a
// hybrid delivery split: gates r,z are staged chunk-wise into LDS (256 KB
// unique per block per step, then read 8x from the LDS pipe ~85 B/cyc);
// gate n streams from L1 as before (~63 B/cyc). The two pipes overlap,
// cutting the 3 MB single-pipe delivery (R6..R11's measured 20+us wall) to
// max(~8us VMEM, ~10us LDS). FMA sequence per (b,j) is UNCHANGED ->
// bit-identical h.
__global__ __launch_bounds__(512) void gru_step_kernel(
    const float* __restrict__ x, const float* __restrict__ meta,
    const float* __restrict__ WihT, const float* __restrict__ WhhP,
    const float* __restrict__ bih, const float* __restrict__ bhh,
    const float* __restrict__ h_in, float* __restrict__ h_out, int t)
{
  __shared__ __align__(16) float hs[16 * Hd];            // 32 KB h tile
  __shared__ __align__(16) float4 wlds[2][CK * 2 * 64];  // 2 x 16 KB (r,z chunks)
  const int tid = threadIdx.x;
  const int jl  = tid & 63;
  const int rg  = tid >> 6;                      // wave 0..7 -> rows 2rg, 2rg+1
  const int j0  = blockIdx.y * 64;
  const int j   = j0 + jl;
  const int b0  = blockIdx.x * 16;

  const float4* __restrict__ W4 = (const float4*)WhhP;

  // stage this block's 16x512 h tile into LDS (coalesced float4)
  for (int i = tid; i < 16 * Hd / 4; i += 512)
    *(float4*)&hs[i * 4] = *(const float4*)&h_in[b0 * Hd + i * 4];

  // stage r,z weights for chunk c into buffer buf
  auto stage = [&](int c, int buf) {
    for (int i = tid; i < CK * 2 * 64; i += 512) {
      const int kk   = i >> 7;          // 0..CK-1
      const int rem  = i & 127;
      const int gate = rem >> 6;        // 0=r, 1=z
      const int col  = rem & 63;
      wlds[buf][i] = W4[((c * CK + kk) * 3 + gate) * PJ + j0 + col];
    }
  };
  stage(0, 0);
  __syncthreads();

  float ar0 = 0.f, az0 = 0.f, an0 = 0.f;
  float ar1 = 0.f, az1 = 0.f, an1 = 0.f;
  constexpr int NCHUNK = (Hd / 4) / CK;   // 16
  for (int c = 0; c < NCHUNK; ++c) {
    const int buf = c & 1;
    if (c + 1 < NCHUNK) stage(c + 1, buf ^ 1);
    const float4* __restrict__ wl = &wlds[buf][0];
#pragma unroll
    for (int kk = 0; kk < CK; ++kk) {
      const int k4 = c * CK + kk;
      const float4 wr = wl[(kk * 2 + 0) * 64 + jl];
      const float4 wz = wl[(kk * 2 + 1) * 64 + jl];
      const float4 wn = W4[(k4 * 3 + 2) * PJ + j];
      const float4 h0 = *(const float4*)&hs[(rg * 2 + 0) * Hd + k4 * 4];  // broadcast
      const float4 h1 = *(const float4*)&hs[(rg * 2 + 1) * Hd + k4 * 4];
      ar0 += wr.x * h0.x + wr.y * h0.y + wr.z * h0.z + wr.w * h0.w;
      az0 += wz.x * h0.x + wz.y * h0.y + wz.z * h0.z + wz.w * h0.w;
      an0 += wn.x * h0.x + wn.y * h0.y + wn.z * h0.z + wn.w * h0.w;
      ar1 += wr.x * h1.x + wr.y * h1.y + wr.z * h1.z + wr.w * h1.w;
      az1 += wz.x * h1.x + wz.y * h1.y + wz.z * h1.z + wz.w * h1.w;
      an1 += wn.x * h1.x + wn.y * h1.y + wn.z * h1.z + wn.w * h1.w;
    }
    __syncthreads();
  }

  const float bihr = bih[j], bihz = bih[512 + j], bihn = bih[1024 + j];
  const float bhhr = bhh[j], bhhz = bhh[512 + j], bhhn = bhh[1024 + j];
  float wir[8], wiz[8], win[8];
#pragma unroll
  for (int kk = 0; kk < 8; ++kk) {
    wir[kk] = WihT[kk * H3d + j];
    wiz[kk] = WihT[kk * H3d + 512 + j];
    win[kk] = WihT[kk * H3d + 1024 + j];
  }

#pragma unroll
  for (int m = 0; m < 2; ++m) {
    const int bl = rg * 2 + m;
    const int b  = b0 + bl;
    const float4 xv = *(const float4*)&x[(b * Nseq + t) * DX];
    const float4 mv = *(const float4*)&meta[b * MET];
    float xm[8] = { xv.x, xv.y, xv.z, xv.w, mv.x, mv.y, mv.z, mv.w };
    float gr = bihr, gz = bihz, gn = bihn;
#pragma unroll
    for (int kk = 0; kk < 8; ++kk) {
      gr += xm[kk] * wir[kk];
      gz += xm[kk] * wiz[kk];
      gn += xm[kk] * win[kk];
    }
    const float ghr = (m ? ar1 : ar0) + bhhr;
    const float ghz = (m ? az1 : az0) + bhhz;
    const float ghn = (m ? an1 : an0) + bhhn;
    const float r = sigmoid_f(gr + ghr);
    const float z = sigmoid_f(gz + ghz);
    const float n = tanhf(gn + r * ghn);
    const float hold = hs[bl * Hd + j];
    h_out[b * Hd + j] = (1.f - z) * n + z * hold;
  }
}

// ---------------- encoder layer 1: relu(A @ W^T + b) ----------------
__global__ __launch_bounds__(256) void gemm_relu_kernel(
    const float* __restrict__ A, const float* __restrict__ WP,
    const float* __restrict__ bias, float* __restrict__ Cout)
{
  __shared__ __align__(16) float as[16 * Hd];
  const int tid  = threadIdx.x;
  const int jl   = tid & 63;
  const int bsub = tid >> 6;
  const int j    = blockIdx.y * 64 + jl;
  const int b0   = blockIdx.x * 16;

  for (int i = tid; i < 16 * Hd; i += 256) as[i] = A[b0 * Hd + i];
  __syncthreads();

  float acc[4] = {0.f, 0.f, 0.f, 0.f};
#pragma unroll 2
  for (int k4 = 0; k4 < Hd / 4; ++k4) {
    const float4 w = *(const float4*)&WP[(k4 * Hd + j) * 4];
#pragma unroll
    for (int m = 0; m < 4; ++m) {
      const float4 av = *(const float4*)&as[(bsub * 4 + m) * Hd + k4 * 4];
      acc[m] += w.x * av.x + w.y * av.y + w.z * av.z + w.w * av.w;
    }
  }
  const float bj = bias[j];
#pragma unroll
  for (int m = 0; m < 4; ++m) {
    const int b = b0 + bsub * 4 + m;
    float v = acc[m] + bj;
    Cout[b * Hd + j] = v > 0.f ? v : 0.f;
  }
}

// ---------------- encoder layer 2 + reparam: z0 = eps*std + mean ----------------
__global__ __launch_bounds__(256) void enc2_z0_kernel(
    const float* __restrict__ O1, const float* __restrict__ W2P,  // [k4][1024][4]
    const float* __restrict__ b2, const float* __restrict__ eps,
    float* __restrict__ z0)
{
  __shared__ __align__(16) float as[16 * Hd];
  const int tid  = threadIdx.x;
  const int jl   = tid & 63;
  const int bsub = tid >> 6;
  const int j    = blockIdx.y * 64 + jl;
  const int b0   = blockIdx.x * 16;

  for (int i = tid; i < 16 * Hd; i += 256) as[i] = O1[b0 * Hd + i];
  __syncthreads();

  float am[4] = {0.f, 0.f, 0.f, 0.f};
  float asd[4] = {0.f, 0.f, 0.f, 0.f};
#pragma unroll 2
  for (int k4 = 0; k4 < Hd / 4; ++k4) {
    const float4 wm = *(const float4*)&W2P[(k4 * 1024 + j) * 4];
    const float4 ws = *(const float4*)&W2P[(k4 * 1024 + 512 + j) * 4];
#pragma unroll
    for (int m = 0; m < 4; ++m) {
      const float4 av = *(const float4*)&as[(bsub * 4 + m) * Hd + k4 * 4];
      am[m]  += wm.x * av.x + wm.y * av.y + wm.z * av.z + wm.w * av.w;
      asd[m] += ws.x * av.x + ws.y * av.y + ws.z * av.z + ws.w * av.w;
    }
  }
  const float bm = b2[j], bs = b2[512 + j];
#pragma unroll
  for (int m = 0; m < 4; ++m) {
    const int b = b0 + bsub * 4 + m;
    const float mean = am[m] + bm;
    const float sd   = asd[m] + bs;
    z0[b * Hd + j] = eps[b * Hd + j] * sd + mean;
  }
}

// ---------------- adaptive Dopri5 ODE solve + final FC ----------------
// 256 blocks x 512 threads, GE=2. Dedupe: thread j (0..511) computes output j
// for BOTH elements -> one weight float4 feeds 8 FMA (was 4), halving weight
// delivery to 2 MB/drift/CU (the measured wall was the 4 MB duplicate stream:
// both eh-groups loaded identical rows). Per-(j,element) matvec FMA order is
// unchanged -> drift outputs bit-identical; only the block-reduction tree has
// more leaves (er differs in last ulp at most).
__global__ __launch_bounds__(512) void ode_fc_kernel(
    const float* __restrict__ x, const float* __restrict__ meta,
    const float* __restrict__ z0in,
    const float* __restrict__ W1P, const float* __restrict__ b1v,
    const float* __restrict__ W2P, const float* __restrict__ b2v,
    const float* __restrict__ fcW, const float* __restrict__ fcb,
    float* __restrict__ outp)
{
  constexpr int GE = 2;
  __shared__ __align__(16) float zsh[GE][Hd];   // 4 KB
  __shared__ float red[8 * GE];
  const int tid = threadIdx.x;
  const int j   = tid;                 // output row (both elements)
  const int bg0 = blockIdx.x * GE;

  const float b1r = b1v[j];
  const float b2r = b2v[j];

  // drift for output j, both elements
  auto drift = [&](const float (&in)[2], float (&out)[2]) {
    __syncthreads();
    zsh[0][j] = in[0];
    zsh[1][j] = in[1];
    __syncthreads();
    float u0 = b1r, u1 = b1r;
#pragma unroll 4
    for (int k4 = 0; k4 < Hd / 4; ++k4) {
      const float4 w  = *(const float4*)&W1P[(k4 * PJ + j) * 4];
      const float4 z0 = *(const float4*)&zsh[0][k4 * 4];   // broadcast
      const float4 z1 = *(const float4*)&zsh[1][k4 * 4];   // broadcast
      u0 += w.x * z0.x + w.y * z0.y + w.z * z0.z + w.w * z0.w;
      u1 += w.x * z1.x + w.y * z1.y + w.z * z1.z + w.w * z1.w;
    }
    u0 = selu_f(u0); u1 = selu_f(u1);
    __syncthreads();
    zsh[0][j] = u0;
    zsh[1][j] = u1;
    __syncthreads();
    float v0 = b2r, v1 = b2r;
#pragma unroll 4
    for (int k4 = 0; k4 < Hd / 4; ++k4) {
      const float4 w  = *(const float4*)&W2P[(k4 * PJ + j) * 4];
      const float4 z0 = *(const float4*)&zsh[0][k4 * 4];
      const float4 z1 = *(const float4*)&zsh[1][k4 * 4];
      v0 += w.x * z0.x + w.y * z0.y + w.z * z0.z + w.w * z0.w;
      v1 += w.x * z1.x + w.y * z1.y + w.z * z1.z + w.w * z1.w;
    }
    out[0] = v0; out[1] = v1;
  };

  // block-wide per-element sum; all threads receive identical results
  auto blocksum = [&](float (&v)[GE], float (&s)[GE]) {
#pragma unroll
    for (int off = 32; off > 0; off >>= 1) {
#pragma unroll
      for (int g = 0; g < GE; ++g) v[g] += __shfl_down(v[g], off);
    }
    __syncthreads();
    if ((tid & 63) == 0) {
      const int w = tid >> 6;
#pragma unroll
      for (int g = 0; g < GE; ++g) red[w * GE + g] = v[g];
    }
    __syncthreads();
#pragma unroll
    for (int g = 0; g < GE; ++g) {
      float t = 0.f;
#pragma unroll
      for (int w = 0; w < 8; ++w) t += red[w * GE + g];
      s[g] = t;
    }
  };

  float y[2], f[2], py[2], pf[2], ym[2];
  float tcur[GE], dtv[GE], tfin[GE], ptv[GE], pdt[GE];
  bool act[GE];

#pragma unroll
  for (int g = 0; g < GE; ++g) {
    y[g]    = z0in[(bg0 + g) * Hd + j];
    tcur[g] = x[((bg0 + g) * Nseq + 0) * DX];
    tfin[g] = x[((bg0 + g) * Nseq + (Nseq - 1)) * DX];
  }

  drift(y, f);

  // ---- initial step size (Hairer / jax variant) ----
  float sc[2], q0[GE], q1[GE];
#pragma unroll
  for (int l = 0; l < 2; ++l) {
    sc[l] = ATOL_C + RTOL_C * fabsf(y[l]);
    const float a = y[l] / sc[l], b = f[l] / sc[l];
    q0[l] = a * a;
    q1[l] = b * b;
  }
  float d0s[GE], d1s[GE];
  blocksum(q0, d0s);
  blocksum(q1, d1s);
  float h0[GE];
#pragma unroll
  for (int g = 0; g < GE; ++g) {
    const float d0 = sqrtf(d0s[g]), d1 = sqrtf(d1s[g]);
    h0[g] = (d0 < 1e-5f || d1 < 1e-5f) ? 1e-6f : 0.01f * d0 / d1;
  }
  float yin[2], f1h[2];
#pragma unroll
  for (int l = 0; l < 2; ++l) yin[l] = y[l] + h0[l] * f[l];
  drift(yin, f1h);
  float q2[GE];
#pragma unroll
  for (int l = 0; l < 2; ++l) {
    const float dd = (f1h[l] - f[l]) / sc[l];
    q2[l] = dd * dd;
  }
  float d2s[GE];
  blocksum(q2, d2s);
#pragma unroll
  for (int g = 0; g < GE; ++g) {
    const float d1 = sqrtf(d1s[g]);
    const float d2 = sqrtf(d2s[g]) / h0[g];
    const float h1 = (d1 <= 1e-15f && d2 <= 1e-15f)
                 ? fmaxf(1e-6f, h0[g] * 1e-3f)
                 : powf(0.01f / (d1 + d2), 0.2f);   // jax uses d1+d2 here
    dtv[g] = fminf(100.f * h0[g], h1);
    ptv[g] = tcur[g]; pdt[g] = dtv[g];
    act[g] = (tcur[g] < tfin[g]) && (dtv[g] > 0.f);
  }
#pragma unroll
  for (int l = 0; l < 2; ++l) { py[l] = y[l]; pf[l] = f[l]; ym[l] = y[l]; }

  // ---- adaptive stepping loop ----
  float k2[2], k3[2], k4v[2], k5[2], k6[2], k7[2], y1v[2];
  for (int iter = 0; iter < 4000; ++iter) {
    if (!(act[0] || act[1])) break;

#pragma unroll
    for (int l = 0; l < 2; ++l) yin[l] = y[l] + dtv[l] * (SB10 * f[l]);
    drift(yin, k2);

#pragma unroll
    for (int l = 0; l < 2; ++l)
      yin[l] = y[l] + dtv[l] * (SB20 * f[l] + SB21 * k2[l]);
    drift(yin, k3);

#pragma unroll
    for (int l = 0; l < 2; ++l)
      yin[l] = y[l] + dtv[l] * (SB30 * f[l] + SB31 * k2[l] + SB32 * k3[l]);
    drift(yin, k4v);

#pragma unroll
    for (int l = 0; l < 2; ++l)
      yin[l] = y[l] + dtv[l] * (SB40 * f[l] + SB41 * k2[l] + SB42 * k3[l] + SB43 * k4v[l]);
    drift(yin, k5);

#pragma unroll
    for (int l = 0; l < 2; ++l)
      yin[l] = y[l] + dtv[l] * (SB50 * f[l] + SB51 * k2[l] + SB52 * k3[l] + SB53 * k4v[l] + SB54 * k5[l]);
    drift(yin, k6);

#pragma unroll
    for (int l = 0; l < 2; ++l)
      y1v[l] = y[l] + dtv[l] * (CS0 * f[l] + CS2 * k3[l] + CS3 * k4v[l] + CS4 * k5[l] + CS5 * k6[l]);
    drift(y1v, k7);

    float rs[GE];
#pragma unroll
    for (int l = 0; l < 2; ++l) {
      const float yerr = dtv[l] * (CE0 * f[l] + CE2 * k3[l] + CE3 * k4v[l] + CE4 * k5[l] + CE5 * k6[l] + CE6 * k7[l]);
      const float tol = ATOL_C + RTOL_C * fmaxf(fabsf(y[l]), fabsf(y1v[l]));
      const float r = yerr / tol;
      rs[l] = r * r;
    }
    float rsum[GE];
    blocksum(rs, rsum);

    bool acc[GE];
#pragma unroll
    for (int g = 0; g < GE; ++g)
      acc[g] = act[g] && (sqrtf(rsum[g] * (1.0f / Hd)) <= 1.0f);

#pragma unroll
    for (int l = 0; l < 2; ++l) {
      if (acc[l]) {
        ym[l] = y[l] + dtv[l] * (CM0 * f[l] + CM2 * k3[l] + CM3 * k4v[l] + CM4 * k5[l] + CM5 * k6[l] + CM6 * k7[l]);
        py[l] = y[l]; pf[l] = f[l];
        y[l] = y1v[l]; f[l] = k7[l];
      }
    }
#pragma unroll
    for (int g = 0; g < GE; ++g) {
      if (!act[g]) continue;
      const float er = sqrtf(rsum[g] * (1.0f / Hd));
      if (acc[g]) {
        ptv[g] = tcur[g]; pdt[g] = dtv[g];
        tcur[g] = tcur[g] + dtv[g];
      }
      float dtn;
      if (er == 0.0f) {
        dtn = dtv[g] * 10.0f;
      } else {
        const float dfac = (er < 1.0f) ? 1.0f : 0.2f;
        const float fac = fminf(10.0f, fmaxf(0.9f * powf(er, -0.2f), dfac));
        dtn = dtv[g] * fac;
      }
      dtv[g] = fmaxf(dtn, 0.0f);
      act[g] = (tcur[g] < tfin[g]) && (dtv[g] > 0.0f);
    }
  }

  // ---- interpolate at t_final (4th-order fit) and fused FC ----
  const float fcw = fcW[j];
  float s[GE];
#pragma unroll
  for (int l = 0; l < 2; ++l) {
    const float denom = tcur[l] - ptv[l];
    const float xr = (tfin[l] - ptv[l]) / denom;
    const float dy0 = pdt[l] * pf[l];
    const float dy1 = pdt[l] * f[l];
    const float aa = -2.f * dy0 + 2.f * dy1 - 8.f * py[l] - 8.f * y[l] + 16.f * ym[l];
    const float bb =  5.f * dy0 - 3.f * dy1 + 18.f * py[l] + 14.f * y[l] - 32.f * ym[l];
    const float cc = -4.f * dy0 + 1.f * dy1 - 11.f * py[l] - 5.f * y[l] + 16.f * ym[l];
    const float dd = dy0;
    const float ee = py[l];
    const float yf = (((aa * xr + bb) * xr + cc) * xr + dd) * xr + ee;
    s[l] = yf * fcw;
  }
  float ssum[GE];
  blocksum(s, ssum);
  if (tid == 0) {
#pragma unroll
    for (int g = 0; g < GE; ++g) {
      float o = ssum[g] + fcb[0];
#pragma unroll
      for (int m = 0; m < MET; ++m) o += meta[(bg0 + g) * MET + m] * fcW[Hd + m];
      outp[bg0 + g] = o;
    }
  }
}

// ---------------- host launcher ----------------
extern "C" void kernel_launch(void* const* d_in, const int* in_sizes, int n_in,
                              void* d_out, int out_size, void* d_ws, size_t ws_size,
                              hipStream_t stream)
{
  (void)in_sizes; (void)n_in; (void)out_size; (void)ws_size;

  const float* x    = (const float*)d_in[0];
  const float* meta = (const float*)d_in[1];
  const float* eps  = (const float*)d_in[2];
  const float* gWih = (const float*)d_in[3];
  const float* gWhh = (const float*)d_in[4];
  const float* gbih = (const float*)d_in[5];
  const float* gbhh = (const float*)d_in[6];
  const float* eW1  = (const float*)d_in[7];
  const float* eb1  = (const float*)d_in[8];
  const float* eW2  = (const float*)d_in[9];
  const float* eb2  = (const float*)d_in[10];
  const float* oW1  = (const float*)d_in[11];
  const float* ob1  = (const float*)d_in[12];
  const float* oW2  = (const float*)d_in[13];
  const float* ob2  = (const float*)d_in[14];
  const float* fcW  = (const float*)d_in[15];
  const float* fcb  = (const float*)d_in[16];
  float* out = (float*)d_out;
  float* ws  = (float*)d_ws;

  // ws layout (floats), padded weight buffers
  float* WhhP = ws + 0;          // 128*3*520*4 = 798720
  float* WihT = ws + 798720;     //   12288
  float* eW1P = ws + 811008;     //  262144
  float* eW2P = ws + 1073152;    //  524288
  float* oW1P = ws + 1597440;    // 128*520*4 = 266240
  float* oW2P = ws + 1863680;    //  266240
  float* hA   = ws + 2129920;    //  262144 (h ping / z0)
  float* hB   = ws + 2392064;    //  262144 (h pong / o1)

  // all 6 weight repacks in one launch (2109440 input elements)
  pack_all_kernel<<<(2109440 + 255) / 256, 256, 0, stream>>>(
      gWhh, gWih, eW1, eW2, oW1, oW2, WhhP, WihT, eW1P, eW2P, oW1P, oW2P);
  hipMemsetAsync(hA, 0, (size_t)Bsz * Hd * sizeof(float), stream);

  // per-step GRU: 256 blocks x 512 threads (R6 shape + hybrid LDS/L1 gates)
  dim3 ggrid(32, 8);
  for (int t = 0; t < Nseq; ++t) {
    const float* hin = (t & 1) ? hB : hA;
    float* hout      = (t & 1) ? hA : hB;
    gru_step_kernel<<<ggrid, 512, 0, stream>>>(x, meta, WihT, WhhP, gbih, gbhh, hin, hout, t);
  }
  // final h in hA (t=63 odd writes hA)
  dim3 egrid(32, 8);
  gemm_relu_kernel<<<egrid, 256, 0, stream>>>(hA, eW1P, eb1, hB);           // o1 -> hB
  enc2_z0_kernel<<<egrid, 256, 0, stream>>>(hB, eW2P, eb2, eps, hA);        // z0 -> hA
  ode_fc_kernel<<<Bsz / 2, 512, 0, stream>>>(x, meta, hA, oW1P, ob1, oW2P, ob2, fcW, fcb, out);
}

// Round 13
// 2369.408 us; speedup vs baseline: 1.9201x; 1.1614x over previous
//
#include <hip/hip_runtime.h>
#include <math.h>

// Problem dims
constexpr int Bsz  = 512;
constexpr int Nseq = 64;
constexpr int DX   = 4;
constexpr int MET  = 4;
constexpr int Hd   = 512;
constexpr int H3d  = 1536;

constexpr int PJ = 520;     // padded j-rows in ODE packed weights (from R11)

constexpr float RTOL_C = 1e-3f;
constexpr float ATOL_C = 1e-5f;

// ---- Dopri5 tableau (exactly as in jax.experimental.ode, f64->f32) ----
constexpr float SB10 = (float)(1.0/5.0);
constexpr float SB20 = (float)(3.0/40.0),  SB21 = (float)(9.0/40.0);
constexpr float SB30 = (float)(44.0/45.0), SB31 = (float)(-56.0/15.0), SB32 = (float)(32.0/9.0);
constexpr float SB40 = (float)(19372.0/6561.0), SB41 = (float)(-25360.0/2187.0),
                SB42 = (float)(64448.0/6561.0), SB43 = (float)(-212.0/729.0);
constexpr float SB50 = (float)(9017.0/3168.0),  SB51 = (float)(-355.0/33.0),
                SB52 = (float)(46732.0/5247.0), SB53 = (float)(49.0/176.0),
                SB54 = (float)(-5103.0/18656.0);
constexpr float CS0 = (float)(35.0/384.0), CS2 = (float)(500.0/1113.0),
                CS3 = (float)(125.0/192.0), CS4 = (float)(-2187.0/6784.0),
                CS5 = (float)(11.0/84.0);
// Shampine error coefficients (c_sol - c_star), as written in jax ode.py
constexpr float CE0 = (float)(35.0/384.0 - 1951.0/21600.0);
constexpr float CE2 = (float)(500.0/1113.0 - 22642.0/50085.0);
constexpr float CE3 = (float)(125.0/192.0 - 451.0/720.0);
constexpr float CE4 = (float)(-2187.0/6784.0 + 12231.0/42400.0);
constexpr float CE5 = (float)(11.0/84.0 - 649.0/6300.0);
constexpr float CE6 = (float)(-1.0/60.0);
// dps_c_mid for interpolation fit
constexpr float CM0 = (float)(6025192743.0/30085553152.0/2.0);
constexpr float CM2 = (float)(51252292925.0/65400821598.0/2.0);
constexpr float CM3 = (float)(-2691868925.0/45128329728.0/2.0);
constexpr float CM4 = (float)(187940372067.0/1594534317056.0/2.0);
constexpr float CM5 = (float)(-1776094331.0/19743644256.0/2.0);
constexpr float CM6 = (float)(11237099.0/235043384.0/2.0);

__device__ __forceinline__ float selu_f(float v) {
  const float scl = 1.0507009873554805f;
  const float alp = 1.6732632423543772f;
  float e = v > 0.f ? v : alp * expm1f(v);
  return scl * e;
}
__device__ __forceinline__ float sigmoid_f(float v) {
  return 1.f / (1.f + expf(-v));
}

// ---------------- fused weight repack (one launch) ----------------
// WhhB: [jt][k4][gate][64][4] -- per j-tile the whole per-step weight read is
//       ONE contiguous 384 KB stream (GRU saw 60 B/cyc with 3 interleaved
//       gate streams vs ODE's 120 B/cyc single stream -- this removes the
//       interleave). oW1P/oW2P: [k4][PJ][4]. eW*P unpadded.
__global__ __launch_bounds__(256) void pack_all_kernel(
    const float* __restrict__ gWhh, const float* __restrict__ gWih,
    const float* __restrict__ eW1,  const float* __restrict__ eW2,
    const float* __restrict__ oW1,  const float* __restrict__ oW2,
    float* __restrict__ WhhB, float* __restrict__ WihT,
    float* __restrict__ eW1P, float* __restrict__ eW2P,
    float* __restrict__ oW1P, float* __restrict__ oW2P)
{
  int i = blockIdx.x * 256 + threadIdx.x;
  if (i < 786432) {                       // gWhh (1536x512)
    const int r = i >> 9, k = i & 511;
    const int gate = r >> 9, jr = r & 511;
    const int jt = jr >> 6, jl = jr & 63;
    const int k4 = k >> 2, kk = k & 3;
    WhhB[((((jt * 128 + k4) * 3 + gate) * 64) + jl) * 4 + kk] = gWhh[i];
  } else if (i < 798720) {                // gWih (1536x8) -> transpose
    const int ii = i - 786432;
    const int r = ii >> 3, c = ii & 7;
    WihT[c * H3d + r] = gWih[ii];
  } else if (i < 1060864) {               // eW1 (512x512)
    const int ii = i - 798720;
    const int r = ii >> 9, k = ii & 511;
    eW1P[(k >> 2) * (Hd * 4) + r * 4 + (k & 3)] = eW1[ii];
  } else if (i < 1585152) {               // eW2 (1024x512)
    const int ii = i - 1060864;
    const int r = ii >> 9, k = ii & 511;
    eW2P[(k >> 2) * (1024 * 4) + r * 4 + (k & 3)] = eW2[ii];
  } else if (i < 1847296) {               // oW1 (512x512), padded
    const int ii = i - 1585152;
    const int r = ii >> 9, k = ii & 511;
    oW1P[((k >> 2) * PJ + r) * 4 + (k & 3)] = oW1[ii];
  } else if (i < 2109440) {               // oW2 (512x512), padded
    const int ii = i - 1847296;
    const int r = ii >> 9, k = ii & 511;
    oW2P[((k >> 2) * PJ + r) * 4 + (k & 3)] = oW2[ii];
  }
}

// ---------------- GRU step: h_out = GRUCell(xm_t, h_in) ----------------
// R6 proven structure (best measured 26us/step): grid (32,8) = 256 blocks
// (1/CU), 512 threads = 8 waves (2/SIMD); wave rg owns rows 2rg, 2rg+1;
// h tile in LDS (broadcast reads). NEW: contiguous-per-block weight stream
// (WhhB[jt] slice: k4-major, gates adjacent) -- address change only, FMA
// order identical -> bit-identical h. R12's LDS-staged variant reverted
// (distinct-address ds_read_b128 at ~85 B/cyc shared across waves was slower
// than the L1 path it replaced).
__global__ __launch_bounds__(512) void gru_step_kernel(
    const float* __restrict__ x, const float* __restrict__ meta,
    const float* __restrict__ WihT, const float* __restrict__ WhhB,
    const float* __restrict__ bih, const float* __restrict__ bhh,
    const float* __restrict__ h_in, float* __restrict__ h_out, int t)
{
  __shared__ __align__(16) float hs[16 * Hd];    // 32 KB h tile
  const int tid = threadIdx.x;
  const int jl  = tid & 63;
  const int rg  = tid >> 6;                      // wave 0..7 -> rows 2rg, 2rg+1
  const int jt  = blockIdx.y;
  const int j   = jt * 64 + jl;
  const int b0  = blockIdx.x * 16;

  const float4* __restrict__ W4 = (const float4*)WhhB + (size_t)jt * 128 * 3 * 64;

  // stage this block's 16x512 h tile into LDS (coalesced float4)
  for (int i = tid; i < 16 * Hd / 4; i += 512)
    *(float4*)&hs[i * 4] = *(const float4*)&h_in[b0 * Hd + i * 4];
  __syncthreads();

  float ar0 = 0.f, az0 = 0.f, an0 = 0.f;
  float ar1 = 0.f, az1 = 0.f, an1 = 0.f;
#pragma unroll 4
  for (int k4 = 0; k4 < Hd / 4; ++k4) {
    const float4 wr = W4[(k4 * 3 + 0) * 64 + jl];
    const float4 wz = W4[(k4 * 3 + 1) * 64 + jl];
    const float4 wn = W4[(k4 * 3 + 2) * 64 + jl];
    const float4 h0 = *(const float4*)&hs[(rg * 2 + 0) * Hd + k4 * 4];  // broadcast
    const float4 h1 = *(const float4*)&hs[(rg * 2 + 1) * Hd + k4 * 4];
    ar0 += wr.x * h0.x + wr.y * h0.y + wr.z * h0.z + wr.w * h0.w;
    az0 += wz.x * h0.x + wz.y * h0.y + wz.z * h0.z + wz.w * h0.w;
    an0 += wn.x * h0.x + wn.y * h0.y + wn.z * h0.z + wn.w * h0.w;
    ar1 += wr.x * h1.x + wr.y * h1.y + wr.z * h1.z + wr.w * h1.w;
    az1 += wz.x * h1.x + wz.y * h1.y + wz.z * h1.z + wz.w * h1.w;
    an1 += wn.x * h1.x + wn.y * h1.y + wn.z * h1.z + wn.w * h1.w;
  }

  const float bihr = bih[j], bihz = bih[512 + j], bihn = bih[1024 + j];
  const float bhhr = bhh[j], bhhz = bhh[512 + j], bhhn = bhh[1024 + j];
  float wir[8], wiz[8], win[8];
#pragma unroll
  for (int kk = 0; kk < 8; ++kk) {
    wir[kk] = WihT[kk * H3d + j];
    wiz[kk] = WihT[kk * H3d + 512 + j];
    win[kk] = WihT[kk * H3d + 1024 + j];
  }

#pragma unroll
  for (int m = 0; m < 2; ++m) {
    const int bl = rg * 2 + m;
    const int b  = b0 + bl;
    const float4 xv = *(const float4*)&x[(b * Nseq + t) * DX];
    const float4 mv = *(const float4*)&meta[b * MET];
    float xm[8] = { xv.x, xv.y, xv.z, xv.w, mv.x, mv.y, mv.z, mv.w };
    float gr = bihr, gz = bihz, gn = bihn;
#pragma unroll
    for (int kk = 0; kk < 8; ++kk) {
      gr += xm[kk] * wir[kk];
      gz += xm[kk] * wiz[kk];
      gn += xm[kk] * win[kk];
    }
    const float ghr = (m ? ar1 : ar0) + bhhr;
    const float ghz = (m ? az1 : az0) + bhhz;
    const float ghn = (m ? an1 : an0) + bhhn;
    const float r = sigmoid_f(gr + ghr);
    const float z = sigmoid_f(gz + ghz);
    const float n = tanhf(gn + r * ghn);
    const float hold = hs[bl * Hd + j];
    h_out[b * Hd + j] = (1.f - z) * n + z * hold;
  }
}

// ---------------- encoder layer 1: relu(A @ W^T + b) ----------------
__global__ __launch_bounds__(256) void gemm_relu_kernel(
    const float* __restrict__ A, const float* __restrict__ WP,
    const float* __restrict__ bias, float* __restrict__ Cout)
{
  __shared__ __align__(16) float as[16 * Hd];
  const int tid  = threadIdx.x;
  const int jl   = tid & 63;
  const int bsub = tid >> 6;
  const int j    = blockIdx.y * 64 + jl;
  const int b0   = blockIdx.x * 16;

  for (int i = tid; i < 16 * Hd; i += 256) as[i] = A[b0 * Hd + i];
  __syncthreads();

  float acc[4] = {0.f, 0.f, 0.f, 0.f};
#pragma unroll 2
  for (int k4 = 0; k4 < Hd / 4; ++k4) {
    const float4 w = *(const float4*)&WP[(k4 * Hd + j) * 4];
#pragma unroll
    for (int m = 0; m < 4; ++m) {
      const float4 av = *(const float4*)&as[(bsub * 4 + m) * Hd + k4 * 4];
      acc[m] += w.x * av.x + w.y * av.y + w.z * av.z + w.w * av.w;
    }
  }
  const float bj = bias[j];
#pragma unroll
  for (int m = 0; m < 4; ++m) {
    const int b = b0 + bsub * 4 + m;
    float v = acc[m] + bj;
    Cout[b * Hd + j] = v > 0.f ? v : 0.f;
  }
}

// ---------------- encoder layer 2 + reparam: z0 = eps*std + mean ----------------
__global__ __launch_bounds__(256) void enc2_z0_kernel(
    const float* __restrict__ O1, const float* __restrict__ W2P,  // [k4][1024][4]
    const float* __restrict__ b2, const float* __restrict__ eps,
    float* __restrict__ z0)
{
  __shared__ __align__(16) float as[16 * Hd];
  const int tid  = threadIdx.x;
  const int jl   = tid & 63;
  const int bsub = tid >> 6;
  const int j    = blockIdx.y * 64 + jl;
  const int b0   = blockIdx.x * 16;

  for (int i = tid; i < 16 * Hd; i += 256) as[i] = O1[b0 * Hd + i];
  __syncthreads();

  float am[4] = {0.f, 0.f, 0.f, 0.f};
  float asd[4] = {0.f, 0.f, 0.f, 0.f};
#pragma unroll 2
  for (int k4 = 0; k4 < Hd / 4; ++k4) {
    const float4 wm = *(const float4*)&W2P[(k4 * 1024 + j) * 4];
    const float4 ws = *(const float4*)&W2P[(k4 * 1024 + 512 + j) * 4];
#pragma unroll
    for (int m = 0; m < 4; ++m) {
      const float4 av = *(const float4*)&as[(bsub * 4 + m) * Hd + k4 * 4];
      am[m]  += wm.x * av.x + wm.y * av.y + wm.z * av.z + wm.w * av.w;
      asd[m] += ws.x * av.x + ws.y * av.y + ws.z * av.z + ws.w * av.w;
    }
  }
  const float bm = b2[j], bs = b2[512 + j];
#pragma unroll
  for (int m = 0; m < 4; ++m) {
    const int b = b0 + bsub * 4 + m;
    const float mean = am[m] + bm;
    const float sd   = asd[m] + bs;
    z0[b * Hd + j] = eps[b * Hd + j] * sd + mean;
  }
}

// ---------------- adaptive Dopri5 ODE solve + final FC (R12, kept) ----------------
// 256 blocks x 512 threads, GE=2. Thread j computes output j for BOTH
// elements -> one weight float4 feeds 8 FMA; 2 MB/drift/CU delivery.
// Measured 665us, VALUBusy 65% -- near the delivery/VALU floor.
__global__ __launch_bounds__(512) void ode_fc_kernel(
    const float* __restrict__ x, const float* __restrict__ meta,
    const float* __restrict__ z0in,
    const float* __restrict__ W1P, const float* __restrict__ b1v,
    const float* __restrict__ W2P, const float* __restrict__ b2v,
    const float* __restrict__ fcW, const float* __restrict__ fcb,
    float* __restrict__ outp)
{
  constexpr int GE = 2;
  __shared__ __align__(16) float zsh[GE][Hd];   // 4 KB
  __shared__ float red[8 * GE];
  const int tid = threadIdx.x;
  const int j   = tid;                 // output row (both elements)
  const int bg0 = blockIdx.x * GE;

  const float b1r = b1v[j];
  const float b2r = b2v[j];

  // drift for output j, both elements
  auto drift = [&](const float (&in)[2], float (&out)[2]) {
    __syncthreads();
    zsh[0][j] = in[0];
    zsh[1][j] = in[1];
    __syncthreads();
    float u0 = b1r, u1 = b1r;
#pragma unroll 4
    for (int k4 = 0; k4 < Hd / 4; ++k4) {
      const float4 w  = *(const float4*)&W1P[(k4 * PJ + j) * 4];
      const float4 z0 = *(const float4*)&zsh[0][k4 * 4];   // broadcast
      const float4 z1 = *(const float4*)&zsh[1][k4 * 4];   // broadcast
      u0 += w.x * z0.x + w.y * z0.y + w.z * z0.z + w.w * z0.w;
      u1 += w.x * z1.x + w.y * z1.y + w.z * z1.z + w.w * z1.w;
    }
    u0 = selu_f(u0); u1 = selu_f(u1);
    __syncthreads();
    zsh[0][j] = u0;
    zsh[1][j] = u1;
    __syncthreads();
    float v0 = b2r, v1 = b2r;
#pragma unroll 4
    for (int k4 = 0; k4 < Hd / 4; ++k4) {
      const float4 w  = *(const float4*)&W2P[(k4 * PJ + j) * 4];
      const float4 z0 = *(const float4*)&zsh[0][k4 * 4];
      const float4 z1 = *(const float4*)&zsh[1][k4 * 4];
      v0 += w.x * z0.x + w.y * z0.y + w.z * z0.z + w.w * z0.w;
      v1 += w.x * z1.x + w.y * z1.y + w.z * z1.z + w.w * z1.w;
    }
    out[0] = v0; out[1] = v1;
  };

  // block-wide per-element sum; all threads receive identical results
  auto blocksum = [&](float (&v)[GE], float (&s)[GE]) {
#pragma unroll
    for (int off = 32; off > 0; off >>= 1) {
#pragma unroll
      for (int g = 0; g < GE; ++g) v[g] += __shfl_down(v[g], off);
    }
    __syncthreads();
    if ((tid & 63) == 0) {
      const int w = tid >> 6;
#pragma unroll
      for (int g = 0; g < GE; ++g) red[w * GE + g] = v[g];
    }
    __syncthreads();
#pragma unroll
    for (int g = 0; g < GE; ++g) {
      float t = 0.f;
#pragma unroll
      for (int w = 0; w < 8; ++w) t += red[w * GE + g];
      s[g] = t;
    }
  };

  float y[2], f[2], py[2], pf[2], ym[2];
  float tcur[GE], dtv[GE], tfin[GE], ptv[GE], pdt[GE];
  bool act[GE];

#pragma unroll
  for (int g = 0; g < GE; ++g) {
    y[g]    = z0in[(bg0 + g) * Hd + j];
    tcur[g] = x[((bg0 + g) * Nseq + 0) * DX];
    tfin[g] = x[((bg0 + g) * Nseq + (Nseq - 1)) * DX];
  }

  drift(y, f);

  // ---- initial step size (Hairer / jax variant) ----
  float sc[2], q0[GE], q1[GE];
#pragma unroll
  for (int l = 0; l < 2; ++l) {
    sc[l] = ATOL_C + RTOL_C * fabsf(y[l]);
    const float a = y[l] / sc[l], b = f[l] / sc[l];
    q0[l] = a * a;
    q1[l] = b * b;
  }
  float d0s[GE], d1s[GE];
  blocksum(q0, d0s);
  blocksum(q1, d1s);
  float h0[GE];
#pragma unroll
  for (int g = 0; g < GE; ++g) {
    const float d0 = sqrtf(d0s[g]), d1 = sqrtf(d1s[g]);
    h0[g] = (d0 < 1e-5f || d1 < 1e-5f) ? 1e-6f : 0.01f * d0 / d1;
  }
  float yin[2], f1h[2];
#pragma unroll
  for (int l = 0; l < 2; ++l) yin[l] = y[l] + h0[l] * f[l];
  drift(yin, f1h);
  float q2[GE];
#pragma unroll
  for (int l = 0; l < 2; ++l) {
    const float dd = (f1h[l] - f[l]) / sc[l];
    q2[l] = dd * dd;
  }
  float d2s[GE];
  blocksum(q2, d2s);
#pragma unroll
  for (int g = 0; g < GE; ++g) {
    const float d1 = sqrtf(d1s[g]);
    const float d2 = sqrtf(d2s[g]) / h0[g];
    const float h1 = (d1 <= 1e-15f && d2 <= 1e-15f)
                 ? fmaxf(1e-6f, h0[g] * 1e-3f)
                 : powf(0.01f / (d1 + d2), 0.2f);   // jax uses d1+d2 here
    dtv[g] = fminf(100.f * h0[g], h1);
    ptv[g] = tcur[g]; pdt[g] = dtv[g];
    act[g] = (tcur[g] < tfin[g]) && (dtv[g] > 0.f);
  }
#pragma unroll
  for (int l = 0; l < 2; ++l) { py[l] = y[l]; pf[l] = f[l]; ym[l] = y[l]; }

  // ---- adaptive stepping loop ----
  float k2[2], k3[2], k4v[2], k5[2], k6[2], k7[2], y1v[2];
  for (int iter = 0; iter < 4000; ++iter) {
    if (!(act[0] || act[1])) break;

#pragma unroll
    for (int l = 0; l < 2; ++l) yin[l] = y[l] + dtv[l] * (SB10 * f[l]);
    drift(yin, k2);

#pragma unroll
    for (int l = 0; l < 2; ++l)
      yin[l] = y[l] + dtv[l] * (SB20 * f[l] + SB21 * k2[l]);
    drift(yin, k3);

#pragma unroll
    for (int l = 0; l < 2; ++l)
      yin[l] = y[l] + dtv[l] * (SB30 * f[l] + SB31 * k2[l] + SB32 * k3[l]);
    drift(yin, k4v);

#pragma unroll
    for (int l = 0; l < 2; ++l)
      yin[l] = y[l] + dtv[l] * (SB40 * f[l] + SB41 * k2[l] + SB42 * k3[l] + SB43 * k4v[l]);
    drift(yin, k5);

#pragma unroll
    for (int l = 0; l < 2; ++l)
      yin[l] = y[l] + dtv[l] * (SB50 * f[l] + SB51 * k2[l] + SB52 * k3[l] + SB53 * k4v[l] + SB54 * k5[l]);
    drift(yin, k6);

#pragma unroll
    for (int l = 0; l < 2; ++l)
      y1v[l] = y[l] + dtv[l] * (CS0 * f[l] + CS2 * k3[l] + CS3 * k4v[l] + CS4 * k5[l] + CS5 * k6[l]);
    drift(y1v, k7);

    float rs[GE];
#pragma unroll
    for (int l = 0; l < 2; ++l) {
      const float yerr = dtv[l] * (CE0 * f[l] + CE2 * k3[l] + CE3 * k4v[l] + CE4 * k5[l] + CE5 * k6[l] + CE6 * k7[l]);
      const float tol = ATOL_C + RTOL_C * fmaxf(fabsf(y[l]), fabsf(y1v[l]));
      const float r = yerr / tol;
      rs[l] = r * r;
    }
    float rsum[GE];
    blocksum(rs, rsum);

    bool acc[GE];
#pragma unroll
    for (int g = 0; g < GE; ++g)
      acc[g] = act[g] && (sqrtf(rsum[g] * (1.0f / Hd)) <= 1.0f);

#pragma unroll
    for (int l = 0; l < 2; ++l) {
      if (acc[l]) {
        ym[l] = y[l] + dtv[l] * (CM0 * f[l] + CM2 * k3[l] + CM3 * k4v[l] + CM4 * k5[l] + CM5 * k6[l] + CM6 * k7[l]);
        py[l] = y[l]; pf[l] = f[l];
        y[l] = y1v[l]; f[l] = k7[l];
      }
    }
#pragma unroll
    for (int g = 0; g < GE; ++g) {
      if (!act[g]) continue;
      const float er = sqrtf(rsum[g] * (1.0f / Hd));
      if (acc[g]) {
        ptv[g] = tcur[g]; pdt[g] = dtv[g];
        tcur[g] = tcur[g] + dtv[g];
      }
      float dtn;
      if (er == 0.0f) {
        dtn = dtv[g] * 10.0f;
      } else {
        const float dfac = (er < 1.0f) ? 1.0f : 0.2f;
        const float fac = fminf(10.0f, fmaxf(0.9f * powf(er, -0.2f), dfac));
        dtn = dtv[g] * fac;
      }
      dtv[g] = fmaxf(dtn, 0.0f);
      act[g] = (tcur[g] < tfin[g]) && (dtv[g] > 0.0f);
    }
  }

  // ---- interpolate at t_final (4th-order fit) and fused FC ----
  const float fcw = fcW[j];
  float s[GE];
#pragma unroll
  for (int l = 0; l < 2; ++l) {
    const float denom = tcur[l] - ptv[l];
    const float xr = (tfin[l] - ptv[l]) / denom;
    const float dy0 = pdt[l] * pf[l];
    const float dy1 = pdt[l] * f[l];
    const float aa = -2.f * dy0 + 2.f * dy1 - 8.f * py[l] - 8.f * y[l] + 16.f * ym[l];
    const float bb =  5.f * dy0 - 3.f * dy1 + 18.f * py[l] + 14.f * y[l] - 32.f * ym[l];
    const float cc = -4.f * dy0 + 1.f * dy1 - 11.f * py[l] - 5.f * y[l] + 16.f * ym[l];
    const float dd = dy0;
    const float ee = py[l];
    const float yf = (((aa * xr + bb) * xr + cc) * xr + dd) * xr + ee;
    s[l] = yf * fcw;
  }
  float ssum[GE];
  blocksum(s, ssum);
  if (tid == 0) {
#pragma unroll
    for (int g = 0; g < GE; ++g) {
      float o = ssum[g] + fcb[0];
#pragma unroll
      for (int m = 0; m < MET; ++m) o += meta[(bg0 + g) * MET + m] * fcW[Hd + m];
      outp[bg0 + g] = o;
    }
  }
}

// ---------------- host launcher ----------------
extern "C" void kernel_launch(void* const* d_in, const int* in_sizes, int n_in,
                              void* d_out, int out_size, void* d_ws, size_t ws_size,
                              hipStream_t stream)
{
  (void)in_sizes; (void)n_in; (void)out_size; (void)ws_size;

  const float* x    = (const float*)d_in[0];
  const float* meta = (const float*)d_in[1];
  const float* eps  = (const float*)d_in[2];
  const float* gWih = (const float*)d_in[3];
  const float* gWhh = (const float*)d_in[4];
  const float* gbih = (const float*)d_in[5];
  const float* gbhh = (const float*)d_in[6];
  const float* eW1  = (const float*)d_in[7];
  const float* eb1  = (const float*)d_in[8];
  const float* eW2  = (const float*)d_in[9];
  const float* eb2  = (const float*)d_in[10];
  const float* oW1  = (const float*)d_in[11];
  const float* ob1  = (const float*)d_in[12];
  const float* oW2  = (const float*)d_in[13];
  const float* ob2  = (const float*)d_in[14];
  const float* fcW  = (const float*)d_in[15];
  const float* fcb  = (const float*)d_in[16];
  float* out = (float*)d_out;
  float* ws  = (float*)d_ws;

  // ws layout (floats)
  float* WhhB = ws + 0;          // 8*128*3*64*4 = 786432 (contiguous j-tile slices)
  float* WihT = ws + 786432;     //   12288
  float* eW1P = ws + 798720;     //  262144
  float* eW2P = ws + 1060864;    //  524288
  float* oW1P = ws + 1585152;    // 128*520*4 = 266240
  float* oW2P = ws + 1851392;    //  266240
  float* hA   = ws + 2117632;    //  262144 (h ping / z0)
  float* hB   = ws + 2379776;    //  262144 (h pong / o1)

  // all 6 weight repacks in one launch (2109440 input elements)
  pack_all_kernel<<<(2109440 + 255) / 256, 256, 0, stream>>>(
      gWhh, gWih, eW1, eW2, oW1, oW2, WhhB, WihT, eW1P, eW2P, oW1P, oW2P);
  hipMemsetAsync(hA, 0, (size_t)Bsz * Hd * sizeof(float), stream);

  // per-step GRU: 256 blocks x 512 threads (R6 shape, contiguous weight stream)
  dim3 ggrid(32, 8);
  for (int t = 0; t < Nseq; ++t) {
    const float* hin = (t & 1) ? hB : hA;
    float* hout      = (t & 1) ? hA : hB;
    gru_step_kernel<<<ggrid, 512, 0, stream>>>(x, meta, WihT, WhhB, gbih, gbhh, hin, hout, t);
  }
  // final h in hA (t=63 odd writes hA)
  dim3 egrid(32, 8);
  gemm_relu_kernel<<<egrid, 256, 0, stream>>>(hA, eW1P, eb1, hB);           // o1 -> hB
  enc2_z0_kernel<<<egrid, 256, 0, stream>>>(hB, eW2P, eb2, eps, hA);        // z0 -> hA
  ode_fc_kernel<<<Bsz / 2, 512, 0, stream>>>(x, meta, hA, oW1P, ob1, oW2P, ob2, fcW, fcb, out);
}